// Round 9
// baseline (779.361 us; speedup 1.0000x reference)
//
#include <hip/hip_runtime.h>

#define N_NODES 50000
#define N_EDGES 800000
#define N_GRAPHS 256
#define F_IN 9
#define GF_DIM 187
#define HO1 256
#define HO2 512
#define FC1_DIM 128
#define Z_DIM (HO2 + GF_DIM)   // 699

// ---------------- workspace layout (bytes) — proven footprint ----------------
#define OFF_XL1   0UL
#define OFF_XR1   25600000UL
#define OFF_XLR2  0UL
#define OFF_H1    102400000UL
#define OFF_H2    102400000UL
#define OFF_SMALL 153600000UL
#define OFF_DEG    (OFF_SMALL + 0UL)
#define OFF_ROWPTR (OFF_SMALL + 200704UL)
#define OFF_CURSOR (OFF_SMALL + 401408UL)
#define OFF_COL    (OFF_SMALL + 602112UL)
#define OFF_GS     (OFF_SMALL + 3802112UL)
#define OFF_POOLED (OFF_SMALL + 3806208UL)   // 512 KB fp32 pooled
#define OFF_WCAT   (OFF_SMALL + 4330496UL)
#define OFF_BCAT   (OFF_SMALL + 5379072UL)
#define WS_REQUIRED (OFF_SMALL + 5383168UL)   // 158,983,168 (proven)

typedef __attribute__((ext_vector_type(8))) short short8;
typedef __attribute__((ext_vector_type(4))) float floatx4;

// ---------------- bf16 helpers (RTNE) ----------------
__device__ __forceinline__ unsigned short pk1(float a) {
    unsigned u = __float_as_uint(a);
    return (unsigned short)((u + 0x7fffu + ((u >> 16) & 1u)) >> 16);
}
__device__ __forceinline__ unsigned pk_bf16(float a, float b) {
    unsigned ua = __float_as_uint(a), ub = __float_as_uint(b);
    ua = (ua + 0x7fffu + ((ua >> 16) & 1u)) >> 16;
    ub = (ub + 0x7fffu + ((ub >> 16) & 1u)) & 0xffff0000u;
    return ua | ub;
}

template <int NW>
__device__ __forceinline__ void ldrow(const unsigned short* p, unsigned* w) {
    if constexpr (NW == 2) *(uint2*)w = *(const uint2*)p;
    else                   *(uint4*)w = *(const uint4*)p;
}
template <int NW>
__device__ __forceinline__ void unpk(const unsigned* w, float* f) {
#pragma unroll
    for (int i = 0; i < NW; ++i) {
        f[2 * i]     = __uint_as_float(w[i] << 16);
        f[2 * i + 1] = __uint_as_float(w[i] & 0xffff0000u);
    }
}

// factored-leakyrelu logit partial: q = sum(a06*v + a04*|v|), v = xv+xrv
template <int VE>
__device__ __forceinline__ float logit_f(const float* xv, const float* xrv,
                                         const float* a06, const float* a04) {
    float qa = 0.f, qb = 0.f;
#pragma unroll
    for (int j = 0; j < VE; ++j) {
        float v = xv[j] + xrv[j];
        qa = fmaf(a06[j], v, qa);
        qb = fmaf(a04[j], fabsf(v), qb);
    }
    return qa + qb;
}

// ---------------- diagnostic fallback (ws too small) ----------------
__global__ void diag_kernel(float* out, float v) { out[threadIdx.x] = v; }

// ---------------- CSR build ----------------
__global__ __launch_bounds__(256) void zero_deg_kernel(int* __restrict__ deg) {
    int i = blockIdx.x * 256 + threadIdx.x;
    if (i < N_NODES) deg[i] = 0;
}

__global__ __launch_bounds__(256) void count_kernel(const int* __restrict__ ei,
                                                    int* __restrict__ deg) {
    int e = blockIdx.x * 256 + threadIdx.x;
    if (e < N_EDGES) atomicAdd(&deg[ei[N_EDGES + e]], 1);
}

__global__ __launch_bounds__(1024) void scan_kernel(const int* __restrict__ deg,
                                                    int* __restrict__ rowptr,
                                                    int* __restrict__ cursor) {
    __shared__ int part[1024];
    const int t = threadIdx.x;
    const int CH = (N_NODES + 1023) / 1024;   // 49
    int lo = t * CH;
    int hi = lo + CH; if (hi > N_NODES) hi = N_NODES;
    int s = 0;
    for (int i = lo; i < hi; ++i) s += deg[i];
    part[t] = s;
    __syncthreads();
    for (int off = 1; off < 1024; off <<= 1) {
        int v = (t >= off) ? part[t - off] : 0;
        __syncthreads();
        part[t] += v;
        __syncthreads();
    }
    int run = part[t] - s;  // exclusive base
    for (int i = lo; i < hi; ++i) {
        int d = deg[i];
        rowptr[i] = run;
        cursor[i] = run;
        run += d;
    }
    if (t == 1023) rowptr[N_NODES] = part[1023];
}

__global__ __launch_bounds__(256) void fill_kernel(const int* __restrict__ ei,
                                                   int* __restrict__ cursor,
                                                   int* __restrict__ col) {
    int e = blockIdx.x * 256 + threadIdx.x;
    if (e < N_EDGES) {
        int d = ei[N_EDGES + e];
        int pos = atomicAdd(&cursor[d], 1);
        col[pos] = ei[e];
    }
}

// ---------------- layer-1 linear (K=9), bf16 outputs ----------------
__global__ __launch_bounds__(256) void mm1_kernel(const float* __restrict__ x,
                                                  const float* __restrict__ Wl,
                                                  const float* __restrict__ bl,
                                                  const float* __restrict__ Wr,
                                                  const float* __restrict__ br,
                                                  unsigned short* __restrict__ xl,
                                                  unsigned short* __restrict__ xr) {
    __shared__ float xs[F_IN];
    const int n = blockIdx.x;
    const int t = threadIdx.x;
    if (t < F_IN) xs[t] = x[n * F_IN + t];
    __syncthreads();
    float sl = bl[t], sr = br[t];
#pragma unroll
    for (int k = 0; k < F_IN; ++k) {
        float xv = xs[k];
        sl += xv * Wl[k * HO1 + t];
        sr += xv * Wr[k * HO1 + t];
    }
    xl[(size_t)n * HO1 + t] = pk1(sl);
    xr[(size_t)n * HO1 + t] = pk1(sr);
}

// ---------------- pack Wl2|Wr2 -> Wt bf16 [1024 n][256 k] (transposed) ----------------
__global__ __launch_bounds__(256) void pack_w2_kernel(const float* __restrict__ Wl2,
                                                      const float* __restrict__ Wr2,
                                                      const float* __restrict__ bl2,
                                                      const float* __restrict__ br2,
                                                      unsigned short* __restrict__ Wt,
                                                      float* __restrict__ bcat) {
    int i = blockIdx.x * 256 + threadIdx.x;   // 0 .. 1024*256-1
    int n = i >> 8, k = i & 255;
    float w = (n < HO2) ? Wl2[k * HO2 + n] : Wr2[k * HO2 + (n - HO2)];
    Wt[i] = pk1(w);
    if (i < 1024) bcat[i] = (i < HO2) ? bl2[i] : br2[i - HO2];
}

// ---------------- layer-2 linear: bf16 MFMA [50000,256] @ [256,1024] -> bf16 ----------------
// 128x128 tile, BK=32, 4 waves; LDS rows padded to 40 shorts (no 8-way conflicts)
#define LP 40
__global__ __launch_bounds__(256) void mm2_mfma_kernel(
    const unsigned short* __restrict__ A,    // h1 bf16 [N,256]
    const unsigned short* __restrict__ Bt,   // Wt bf16 [1024][256]
    const float* __restrict__ bias,          // bcat [1024]
    unsigned short* __restrict__ C) {        // xlr2 bf16 [N,1024]
    __shared__ unsigned short As[128 * LP];  // 10 KB
    __shared__ unsigned short Bs[128 * LP];  // 10 KB
    const int t = threadIdx.x;
    const int lane = t & 63;
    const int w = t >> 6;
    const int wr = w >> 1, wc = w & 1;       // wave quadrant (64x64)
    const int l15 = lane & 15, kq = lane >> 4;
    const int row0 = blockIdx.y * 128;
    const int col0 = blockIdx.x * 128;

    floatx4 acc[4][4] = {};
    for (int k0 = 0; k0 < 256; k0 += 32) {
        if (k0) __syncthreads();
        int c1 = t, c2 = t + 256;
        int ar1 = row0 + (c1 >> 2); ar1 = ar1 < N_NODES ? ar1 : N_NODES - 1;
        int ar2 = row0 + (c2 >> 2); ar2 = ar2 < N_NODES ? ar2 : N_NODES - 1;
        uint4 va1 = *(const uint4*)(A + (size_t)ar1 * 256 + k0 + (c1 & 3) * 8);
        uint4 va2 = *(const uint4*)(A + (size_t)ar2 * 256 + k0 + (c2 & 3) * 8);
        uint4 vb1 = *(const uint4*)(Bt + (size_t)(col0 + (c1 >> 2)) * 256 + k0 + (c1 & 3) * 8);
        uint4 vb2 = *(const uint4*)(Bt + (size_t)(col0 + (c2 >> 2)) * 256 + k0 + (c2 & 3) * 8);
        *(uint4*)&As[(c1 >> 2) * LP + (c1 & 3) * 8] = va1;
        *(uint4*)&As[(c2 >> 2) * LP + (c2 & 3) * 8] = va2;
        *(uint4*)&Bs[(c1 >> 2) * LP + (c1 & 3) * 8] = vb1;
        *(uint4*)&Bs[(c2 >> 2) * LP + (c2 & 3) * 8] = vb2;
        __syncthreads();

        short8 af[4], bf[4];
#pragma unroll
        for (int i = 0; i < 4; ++i)
            af[i] = *(const short8*)&As[(wr * 64 + i * 16 + l15) * LP + kq * 8];
#pragma unroll
        for (int j = 0; j < 4; ++j)
            bf[j] = *(const short8*)&Bs[(wc * 64 + j * 16 + l15) * LP + kq * 8];
#pragma unroll
        for (int i = 0; i < 4; ++i)
#pragma unroll
            for (int j = 0; j < 4; ++j)
                acc[i][j] = __builtin_amdgcn_mfma_f32_16x16x32_bf16(
                    af[i], bf[j], acc[i][j], 0, 0, 0);
    }
    // epilogue: C/D layout col=lane&15, row=(lane>>4)*4+reg
#pragma unroll
    for (int j = 0; j < 4; ++j) {
        int col = col0 + wc * 64 + j * 16 + l15;
        float bj = bias[col];
#pragma unroll
        for (int i = 0; i < 4; ++i) {
            int rbase = row0 + wr * 64 + i * 16 + kq * 4;
            floatx4 v = acc[i][j];
#pragma unroll
            for (int r = 0; r < 4; ++r) {
                int row = rbase + r;
                if (row < N_NODES) C[(size_t)row * 1024 + col] = pk1(v[r] + bj);
            }
        }
    }
}

// ---------------- fused GATv2 node kernel ----------------
// GROUPS lane-groups per wave, each processing its own edges (own s/acc partials,
// merged by shfl_xor(32) at the end). Ring of 2 pair-buffers gives prefetch
// distance = 2 iterations (~2x compute latency) to cover the gather latency.
// Invalid/tail edges: clamped index + zero weight (all loop bounds wave-uniform).
template <int O, int GROUPS>
__global__ __launch_bounds__(256, 4) void gat_node_kernel(
    const unsigned short* __restrict__ xl_, const unsigned short* __restrict__ xr_,
    int stride,
    const int* __restrict__ rowptr, const int* __restrict__ col,
    const float* __restrict__ att, const float* __restrict__ bias,
    const float* __restrict__ bng, const float* __restrict__ bnb,
    const float* __restrict__ bnm, const float* __restrict__ bnv,
    unsigned short* __restrict__ out_) {
    constexpr int TOT = 4 * O;        // row length in bf16
    constexpr int GS  = 64 / GROUPS;  // lanes per group
    constexpr int VE  = TOT / GS;     // 8 for both layers
    constexpr int NW  = VE / 2;       // 4 (uint4 loads)
    constexpr int LPH = O / VE;       // lanes per head within group (8 or 16)
    const int wave = threadIdx.x >> 6;
    const int node = blockIdx.x * 4 + wave;
    if (node >= N_NODES) return;
    const int lane = threadIdx.x & 63;
    const int gid  = lane / GS;
    const int gl   = lane % GS;
    const int cbase = gl * VE;

    float xrv[VE], a06[VE], a04[VE], acc[VE], xvA[VE], xvB[VE];
    {
        unsigned w_[NW];
        ldrow<NW>(xr_ + (size_t)node * stride + cbase, w_);
        unpk<NW>(w_, xrv);
#pragma unroll
        for (int v = 0; v < VE; v += 4) {
            float4 b = *(const float4*)(att + cbase + v);
            a06[v] = 0.6f * b.x; a06[v + 1] = 0.6f * b.y;
            a06[v + 2] = 0.6f * b.z; a06[v + 3] = 0.6f * b.w;
            a04[v] = 0.4f * b.x; a04[v + 1] = 0.4f * b.y;
            a04[v + 2] = 0.4f * b.z; a04[v + 3] = 0.4f * b.w;
        }
    }
    // self-loop edge (weight contributed by group 0 only)
    float s;
    {
        unsigned w_[NW];
        ldrow<NW>(xl_ + (size_t)node * stride + cbase, w_);
        unpk<NW>(w_, xvA);
        float q = logit_f<VE>(xvA, xrv, a06, a04);
#pragma unroll
        for (int d = 1; d < LPH; d <<= 1) q += __shfl_xor(q, d, 64);
        float w0 = (gid == 0) ? __expf(q) : 0.f;
        s = w0;
#pragma unroll
        for (int j = 0; j < VE; ++j) acc[j] = w0 * xvA[j];
    }

    const int e0 = rowptr[node], e1 = rowptr[node + 1];
    const int deg = e1 - e0;
    constexpr int PER = 2 * GROUPS;           // edges per wave-iteration
    const int itc = (deg + PER - 1) / PER;
    const int base = e0 + gid * 2;            // this group's first edge index
    unsigned L0a[NW], L0b[NW], L1a[NW], L1b[NW];
    if (itc > 0) {
        int ia = base, ib = base + 1;
        ldrow<NW>(xl_ + (size_t)col[ia < e1 ? ia : 0] * stride + cbase, L0a);
        ldrow<NW>(xl_ + (size_t)col[ib < e1 ? ib : 0] * stride + cbase, L0b);
        int ja = base + PER, jb = ja + 1;
        ldrow<NW>(xl_ + (size_t)col[ja < e1 ? ja : 0] * stride + cbase, L1a);
        ldrow<NW>(xl_ + (size_t)col[jb < e1 ? jb : 0] * stride + cbase, L1b);
    }
    int k = 0;
    while (k < itc) {
        {   // consume L0 (pair k), refill L0 with pair k+2
            int ia = base + k * PER, ib = ia + 1;
            unpk<NW>(L0a, xvA);
            unpk<NW>(L0b, xvB);
            if (k + 2 < itc) {
                int pa = base + (k + 2) * PER, pb = pa + 1;
                ldrow<NW>(xl_ + (size_t)col[pa < e1 ? pa : 0] * stride + cbase, L0a);
                ldrow<NW>(xl_ + (size_t)col[pb < e1 ? pb : 0] * stride + cbase, L0b);
            }
            float q1 = logit_f<VE>(xvA, xrv, a06, a04);
            float q2 = logit_f<VE>(xvB, xrv, a06, a04);
#pragma unroll
            for (int d = 1; d < LPH; d <<= 1) {
                q1 += __shfl_xor(q1, d, 64);
                q2 += __shfl_xor(q2, d, 64);
            }
            float w1 = (ia < e1) ? __expf(q1) : 0.f;
            float w2 = (ib < e1) ? __expf(q2) : 0.f;
            s += w1 + w2;
#pragma unroll
            for (int j = 0; j < VE; ++j)
                acc[j] = fmaf(w1, xvA[j], fmaf(w2, xvB[j], acc[j]));
        }
        ++k;
        if (k >= itc) break;
        {   // consume L1 (pair k), refill L1 with pair k+2
            int ia = base + k * PER, ib = ia + 1;
            unpk<NW>(L1a, xvA);
            unpk<NW>(L1b, xvB);
            if (k + 2 < itc) {
                int pa = base + (k + 2) * PER, pb = pa + 1;
                ldrow<NW>(xl_ + (size_t)col[pa < e1 ? pa : 0] * stride + cbase, L1a);
                ldrow<NW>(xl_ + (size_t)col[pb < e1 ? pb : 0] * stride + cbase, L1b);
            }
            float q1 = logit_f<VE>(xvA, xrv, a06, a04);
            float q2 = logit_f<VE>(xvB, xrv, a06, a04);
#pragma unroll
            for (int d = 1; d < LPH; d <<= 1) {
                q1 += __shfl_xor(q1, d, 64);
                q2 += __shfl_xor(q2, d, 64);
            }
            float w1 = (ia < e1) ? __expf(q1) : 0.f;
            float w2 = (ib < e1) ? __expf(q2) : 0.f;
            s += w1 + w2;
#pragma unroll
            for (int j = 0; j < VE; ++j)
                acc[j] = fmaf(w1, xvA[j], fmaf(w2, xvB[j], acc[j]));
        }
        ++k;
    }
    if constexpr (GROUPS == 2) {   // merge group partials (same element space)
        s += __shfl_xor(s, 32, 64);
#pragma unroll
        for (int j = 0; j < VE; ++j) acc[j] += __shfl_xor(acc[j], 32, 64);
    }
    float r = 1.f / (s + 1e-16f);
    if (GROUPS == 1 || gid == 0) {
        float t[VE];
#pragma unroll
        for (int j = 0; j < VE; ++j) {
            int c = cbase + j;
            float val = acc[j] * r + bias[c];
            float y = bng[c] * (val - bnm[c]) * rsqrtf(bnv[c] + 1e-5f) + bnb[c];
            t[j] = fmaxf(y, 0.f);
        }
        uint4 qo;
        qo.x = pk_bf16(t[0], t[1]);
        qo.y = pk_bf16(t[2], t[3]);
        qo.z = pk_bf16(t[4], t[5]);
        qo.w = pk_bf16(t[6], t[7]);
        *(uint4*)(out_ + (size_t)node * TOT + cbase) = qo;
    }
}

// ---------------- graph boundaries (batch sorted) ----------------
__global__ void gstart_kernel(const int* __restrict__ batch, int* __restrict__ gs) {
    int t = blockIdx.x * blockDim.x + threadIdx.x;
    if (t > N_GRAPHS) return;
    if (t == N_GRAPHS) { gs[N_GRAPHS] = N_NODES; return; }
    int lo = 0, hi = N_NODES;
    while (lo < hi) {
        int mid = (lo + hi) >> 1;
        if (batch[mid] < t) lo = mid + 1; else hi = mid;
    }
    gs[t] = lo;
}

// ---------------- mean pool (h2 bf16 -> pooled fp32), 4 blocks per graph ----------------
__global__ __launch_bounds__(128) void pool_kernel(const unsigned short* __restrict__ h2,
                                                   const int* __restrict__ gs,
                                                   float* __restrict__ pooled) {
    const int g = blockIdx.x >> 2;
    const int quarter = blockIdx.x & 3;
    const int t = threadIdx.x;
    const int c = quarter * 128 + t;
    const int s = gs[g], e = gs[g + 1];
    float a = 0.f;
    for (int r = s; r < e; ++r)
        a += __uint_as_float((unsigned)h2[(size_t)r * HO2 + c] << 16);
    float inv = 1.f / fmaxf((float)(e - s), 1.f);
    pooled[(size_t)g * HO2 + c] = a * inv;
}

// ---------------- MLP head ----------------
__global__ __launch_bounds__(128) void mlp_kernel(const float* __restrict__ pooled,
                                                  const float* __restrict__ gf,
                                                  const float* __restrict__ fc1w,
                                                  const float* __restrict__ fc1b,
                                                  const float* __restrict__ fc2w,
                                                  const float* __restrict__ fc2b,
                                                  float* __restrict__ out) {
    __shared__ float z[704];
    __shared__ float red[2];
    const int g = blockIdx.x, t = threadIdx.x;
    for (int i = t; i < HO2; i += 128) z[i] = pooled[(size_t)g * HO2 + i];
    for (int i = t; i < GF_DIM; i += 128) z[HO2 + i] = gf[(size_t)g * GF_DIM + i];
    __syncthreads();
    float s = fc1b[t];
    for (int k = 0; k < Z_DIM; ++k) s += z[k] * fc1w[k * FC1_DIM + t];
    s = fmaxf(s, 0.f);              // relu (dropout = identity in eval)
    float c = s * fc2w[t];
#pragma unroll
    for (int d = 1; d < 64; d <<= 1) c += __shfl_xor(c, d, 64);
    if ((t & 63) == 0) red[t >> 6] = c;
    __syncthreads();
    if (t == 0) out[g] = red[0] + red[1] + fc2b[0];
}

// ---------------- launch ----------------
extern "C" void kernel_launch(void* const* d_in, const int* in_sizes, int n_in,
                              void* d_out, int out_size, void* d_ws, size_t ws_size,
                              hipStream_t stream) {
    float* out = (float*)d_out;
    if (ws_size < WS_REQUIRED) {
        diag_kernel<<<1, 256, 0, stream>>>(out, (float)(ws_size >> 20));
        return;
    }
    const float* x     = (const float*)d_in[0];
    const int*   ei    = (const int*)d_in[1];
    const int*   batch = (const int*)d_in[2];
    const float* gf    = (const float*)d_in[3];
    const float* Wl1   = (const float*)d_in[4];
    const float* bl1   = (const float*)d_in[5];
    const float* Wr1   = (const float*)d_in[6];
    const float* br1   = (const float*)d_in[7];
    const float* att1  = (const float*)d_in[8];
    const float* bias1 = (const float*)d_in[9];
    const float* bn1g  = (const float*)d_in[10];
    const float* bn1b  = (const float*)d_in[11];
    const float* bn1m  = (const float*)d_in[12];
    const float* bn1v  = (const float*)d_in[13];
    const float* Wl2   = (const float*)d_in[14];
    const float* bl2   = (const float*)d_in[15];
    const float* Wr2   = (const float*)d_in[16];
    const float* br2   = (const float*)d_in[17];
    const float* att2  = (const float*)d_in[18];
    const float* bias2 = (const float*)d_in[19];
    const float* bn2g  = (const float*)d_in[20];
    const float* bn2b  = (const float*)d_in[21];
    const float* bn2m  = (const float*)d_in[22];
    const float* bn2v  = (const float*)d_in[23];
    const float* fc1w  = (const float*)d_in[24];
    const float* fc1b  = (const float*)d_in[25];
    const float* fc2w  = (const float*)d_in[26];
    const float* fc2b  = (const float*)d_in[27];
    char* ws = (char*)d_ws;

    unsigned short* xl1  = (unsigned short*)(ws + OFF_XL1);
    unsigned short* xr1  = (unsigned short*)(ws + OFF_XR1);
    unsigned short* xlr2 = (unsigned short*)(ws + OFF_XLR2);
    unsigned short* h1   = (unsigned short*)(ws + OFF_H1);
    unsigned short* h2   = (unsigned short*)(ws + OFF_H2);
    int* deg     = (int*)(ws + OFF_DEG);
    int* rowptr  = (int*)(ws + OFF_ROWPTR);
    int* cursor  = (int*)(ws + OFF_CURSOR);
    int* col     = (int*)(ws + OFF_COL);
    int* gs      = (int*)(ws + OFF_GS);
    float* pooled= (float*)(ws + OFF_POOLED);
    unsigned short* Wt = (unsigned short*)(ws + OFF_WCAT);
    float* bcat  = (float*)(ws + OFF_BCAT);

    // CSR by destination (self-loops handled in-register by gat kernel)
    zero_deg_kernel<<<(N_NODES + 255) / 256, 256, 0, stream>>>(deg);
    count_kernel<<<(N_EDGES + 255) / 256, 256, 0, stream>>>(ei, deg);
    scan_kernel<<<1, 1024, 0, stream>>>(deg, rowptr, cursor);
    fill_kernel<<<(N_EDGES + 255) / 256, 256, 0, stream>>>(ei, cursor, col);
    gstart_kernel<<<1, 512, 0, stream>>>(batch, gs);

    // layer 1 (bf16 storage, fp32 accumulation); 2 edges/wave via lane-groups
    mm1_kernel<<<N_NODES, 256, 0, stream>>>(x, Wl1, bl1, Wr1, br1, xl1, xr1);
    gat_node_kernel<64, 2><<<(N_NODES + 3) / 4, 256, 0, stream>>>(
        xl1, xr1, HO1, rowptr, col, att1, bias1, bn1g, bn1b, bn1m, bn1v, h1);

    // layer 2 (bf16 MFMA GEMM + bf16 gather)
    pack_w2_kernel<<<1024, 256, 0, stream>>>(Wl2, Wr2, bl2, br2, Wt, bcat);
    mm2_mfma_kernel<<<dim3(8, (N_NODES + 127) / 128), 256, 0, stream>>>(h1, Wt, bcat, xlr2);
    gat_node_kernel<128, 1><<<(N_NODES + 3) / 4, 256, 0, stream>>>(
        xlr2, xlr2 + HO2, 1024, rowptr, col, att2, bias2, bn2g, bn2b, bn2m, bn2v, h2);

    // pool + head
    pool_kernel<<<N_GRAPHS * 4, 128, 0, stream>>>(h2, gs, pooled);
    mlp_kernel<<<N_GRAPHS, 128, 0, stream>>>(pooled, gf, fc1w, fc1b, fc2w, fc2b, out);
}

// Round 10
// 737.852 us; speedup vs baseline: 1.0563x; 1.0563x over previous
//
#include <hip/hip_runtime.h>

#define N_NODES 50000
#define N_EDGES 800000
#define N_GRAPHS 256
#define F_IN 9
#define GF_DIM 187
#define HO1 256
#define HO2 512
#define FC1_DIM 128
#define Z_DIM (HO2 + GF_DIM)   // 699

// ---------------- workspace layout (bytes) — proven footprint ----------------
#define OFF_XL1   0UL
#define OFF_XR1   25600000UL
#define OFF_XLR2  0UL
#define OFF_H1    102400000UL
#define OFF_H2    102400000UL
#define OFF_SMALL 153600000UL
#define OFF_DEG    (OFF_SMALL + 0UL)
#define OFF_ROWPTR (OFF_SMALL + 200704UL)
#define OFF_CURSOR (OFF_SMALL + 401408UL)
#define OFF_COL    (OFF_SMALL + 602112UL)
#define OFF_GS     (OFF_SMALL + 3802112UL)
#define OFF_POOLED (OFF_SMALL + 3806208UL)   // 512 KB fp32 pooled
#define OFF_WCAT   (OFF_SMALL + 4330496UL)
#define OFF_BCAT   (OFF_SMALL + 5379072UL)
#define WS_REQUIRED (OFF_SMALL + 5383168UL)   // 158,983,168 (proven)

typedef __attribute__((ext_vector_type(8))) short short8;
typedef __attribute__((ext_vector_type(4))) float floatx4;

// ---------------- bf16 helpers (RTNE) ----------------
__device__ __forceinline__ unsigned short pk1(float a) {
    unsigned u = __float_as_uint(a);
    return (unsigned short)((u + 0x7fffu + ((u >> 16) & 1u)) >> 16);
}
__device__ __forceinline__ unsigned pk_bf16(float a, float b) {
    unsigned ua = __float_as_uint(a), ub = __float_as_uint(b);
    ua = (ua + 0x7fffu + ((ua >> 16) & 1u)) >> 16;
    ub = (ub + 0x7fffu + ((ub >> 16) & 1u)) & 0xffff0000u;
    return ua | ub;
}

template <int NW>
__device__ __forceinline__ void ldrow(const unsigned short* p, unsigned* w) {
    if constexpr (NW == 2) *(uint2*)w = *(const uint2*)p;
    else                   *(uint4*)w = *(const uint4*)p;
}
template <int NW>
__device__ __forceinline__ void unpk(const unsigned* w, float* f) {
#pragma unroll
    for (int i = 0; i < NW; ++i) {
        f[2 * i]     = __uint_as_float(w[i] << 16);
        f[2 * i + 1] = __uint_as_float(w[i] & 0xffff0000u);
    }
}

// unpack row + factored-leakyrelu logit partial: q = sum(a06*v + a04*|v|)
template <int VE, int NW>
__device__ __forceinline__ float edge_logit(const unsigned* w, const float* xrv,
                                            const float* a06, const float* a04,
                                            float* xv) {
    unpk<NW>(w, xv);
    float qa = 0.f, qb = 0.f;
#pragma unroll
    for (int j = 0; j < VE; ++j) {
        float v = xv[j] + xrv[j];
        qa = fmaf(a06[j], v, qa);
        qb = fmaf(a04[j], fabsf(v), qb);
    }
    return qa + qb;
}

// ---------------- diagnostic fallback (ws too small) ----------------
__global__ void diag_kernel(float* out, float v) { out[threadIdx.x] = v; }

// ---------------- CSR build ----------------
__global__ __launch_bounds__(256) void zero_deg_kernel(int* __restrict__ deg) {
    int i = blockIdx.x * 256 + threadIdx.x;
    if (i < N_NODES) deg[i] = 0;
}

__global__ __launch_bounds__(256) void count_kernel(const int* __restrict__ ei,
                                                    int* __restrict__ deg) {
    int e = blockIdx.x * 256 + threadIdx.x;
    if (e < N_EDGES) atomicAdd(&deg[ei[N_EDGES + e]], 1);
}

__global__ __launch_bounds__(1024) void scan_kernel(const int* __restrict__ deg,
                                                    int* __restrict__ rowptr,
                                                    int* __restrict__ cursor) {
    __shared__ int part[1024];
    const int t = threadIdx.x;
    const int CH = (N_NODES + 1023) / 1024;   // 49
    int lo = t * CH;
    int hi = lo + CH; if (hi > N_NODES) hi = N_NODES;
    int s = 0;
    for (int i = lo; i < hi; ++i) s += deg[i];
    part[t] = s;
    __syncthreads();
    for (int off = 1; off < 1024; off <<= 1) {
        int v = (t >= off) ? part[t - off] : 0;
        __syncthreads();
        part[t] += v;
        __syncthreads();
    }
    int run = part[t] - s;  // exclusive base
    for (int i = lo; i < hi; ++i) {
        int d = deg[i];
        rowptr[i] = run;
        cursor[i] = run;
        run += d;
    }
    if (t == 1023) rowptr[N_NODES] = part[1023];
}

__global__ __launch_bounds__(256) void fill_kernel(const int* __restrict__ ei,
                                                   int* __restrict__ cursor,
                                                   int* __restrict__ col) {
    int e = blockIdx.x * 256 + threadIdx.x;
    if (e < N_EDGES) {
        int d = ei[N_EDGES + e];
        int pos = atomicAdd(&cursor[d], 1);
        col[pos] = ei[e];
    }
}

// ---------------- layer-1 linear (K=9), 8 nodes/block (amortize weight reads) ----------------
__global__ __launch_bounds__(256) void mm1_kernel(const float* __restrict__ x,
                                                  const float* __restrict__ Wl,
                                                  const float* __restrict__ bl,
                                                  const float* __restrict__ Wr,
                                                  const float* __restrict__ br,
                                                  unsigned short* __restrict__ xl,
                                                  unsigned short* __restrict__ xr) {
    __shared__ float xs[8][F_IN];
    const int n0 = blockIdx.x * 8;           // N_NODES divisible by 8
    const int t = threadIdx.x;
    if (t < 8 * F_IN) xs[t / F_IN][t % F_IN] = x[n0 * F_IN + t];
    __syncthreads();
    const float blv = bl[t], brv = br[t];
    float sl[8], sr[8];
#pragma unroll
    for (int i = 0; i < 8; ++i) { sl[i] = blv; sr[i] = brv; }
#pragma unroll
    for (int k = 0; k < F_IN; ++k) {
        float wlk = Wl[k * HO1 + t];
        float wrk = Wr[k * HO1 + t];
#pragma unroll
        for (int i = 0; i < 8; ++i) {
            sl[i] = fmaf(xs[i][k], wlk, sl[i]);
            sr[i] = fmaf(xs[i][k], wrk, sr[i]);
        }
    }
#pragma unroll
    for (int i = 0; i < 8; ++i) {
        xl[(size_t)(n0 + i) * HO1 + t] = pk1(sl[i]);
        xr[(size_t)(n0 + i) * HO1 + t] = pk1(sr[i]);
    }
}

// ---------------- pack Wl2|Wr2 -> Wt bf16 [1024 n][256 k] (transposed) ----------------
__global__ __launch_bounds__(256) void pack_w2_kernel(const float* __restrict__ Wl2,
                                                      const float* __restrict__ Wr2,
                                                      const float* __restrict__ bl2,
                                                      const float* __restrict__ br2,
                                                      unsigned short* __restrict__ Wt,
                                                      float* __restrict__ bcat) {
    int i = blockIdx.x * 256 + threadIdx.x;   // 0 .. 1024*256-1
    int n = i >> 8, k = i & 255;
    float w = (n < HO2) ? Wl2[k * HO2 + n] : Wr2[k * HO2 + (n - HO2)];
    Wt[i] = pk1(w);
    if (i < 1024) bcat[i] = (i < HO2) ? bl2[i] : br2[i - HO2];
}

// ---------------- layer-2 linear: bf16 MFMA, double-buffered LDS pipeline ----------------
// 128x128 tile, BK=32, 4 waves; LDS rows padded to 40 shorts; 2 LDS stages:
// next K-tile's global loads issue BEFORE the MFMA block (latency hidden),
// one barrier per iteration.
#define LP 40
__global__ __launch_bounds__(256) void mm2_mfma_kernel(
    const unsigned short* __restrict__ A,    // h1 bf16 [N,256]
    const unsigned short* __restrict__ Bt,   // Wt bf16 [1024][256]
    const float* __restrict__ bias,          // bcat [1024]
    unsigned short* __restrict__ C) {        // xlr2 bf16 [N,1024]
    __shared__ unsigned short As[2][128 * LP];  // 2 x 10 KB
    __shared__ unsigned short Bs[2][128 * LP];  // 2 x 10 KB
    const int t = threadIdx.x;
    const int lane = t & 63;
    const int w = t >> 6;
    const int wr = w >> 1, wc = w & 1;       // wave quadrant (64x64)
    const int l15 = lane & 15, kq = lane >> 4;
    const int row0 = blockIdx.y * 128;
    const int col0 = blockIdx.x * 128;

    const int c1 = t, c2 = t + 256;
    int ar1 = row0 + (c1 >> 2); ar1 = ar1 < N_NODES ? ar1 : N_NODES - 1;
    int ar2 = row0 + (c2 >> 2); ar2 = ar2 < N_NODES ? ar2 : N_NODES - 1;
    const unsigned short* pa1 = A + (size_t)ar1 * 256 + (c1 & 3) * 8;
    const unsigned short* pa2 = A + (size_t)ar2 * 256 + (c2 & 3) * 8;
    const unsigned short* pb1 = Bt + (size_t)(col0 + (c1 >> 2)) * 256 + (c1 & 3) * 8;
    const unsigned short* pb2 = Bt + (size_t)(col0 + (c2 >> 2)) * 256 + (c2 & 3) * 8;
    const int la1 = (c1 >> 2) * LP + (c1 & 3) * 8;
    const int la2 = (c2 >> 2) * LP + (c2 & 3) * 8;

    uint4 va1, va2, vb1, vb2;
    // prologue: stage k0=0 into buffer 0
    va1 = *(const uint4*)(pa1);  va2 = *(const uint4*)(pa2);
    vb1 = *(const uint4*)(pb1);  vb2 = *(const uint4*)(pb2);
    *(uint4*)&As[0][la1] = va1;  *(uint4*)&As[0][la2] = va2;
    *(uint4*)&Bs[0][la1] = vb1;  *(uint4*)&Bs[0][la2] = vb2;

    floatx4 acc[4][4] = {};
    int buf = 0;
    for (int k0 = 0; k0 < 256; k0 += 32) {
        __syncthreads();             // LDS[buf] ready; previous compute done
        const bool more = (k0 + 32 < 256);
        if (more) {                  // issue next tile's loads early
            va1 = *(const uint4*)(pa1 + k0 + 32);
            va2 = *(const uint4*)(pa2 + k0 + 32);
            vb1 = *(const uint4*)(pb1 + k0 + 32);
            vb2 = *(const uint4*)(pb2 + k0 + 32);
        }
        short8 af[4], bf[4];
#pragma unroll
        for (int i = 0; i < 4; ++i)
            af[i] = *(const short8*)&As[buf][(wr * 64 + i * 16 + l15) * LP + kq * 8];
#pragma unroll
        for (int j = 0; j < 4; ++j)
            bf[j] = *(const short8*)&Bs[buf][(wc * 64 + j * 16 + l15) * LP + kq * 8];
#pragma unroll
        for (int i = 0; i < 4; ++i)
#pragma unroll
            for (int j = 0; j < 4; ++j)
                acc[i][j] = __builtin_amdgcn_mfma_f32_16x16x32_bf16(
                    af[i], bf[j], acc[i][j], 0, 0, 0);
        if (more) {                  // store to the other buffer (no reader yet)
            int nb = 1 - buf;
            *(uint4*)&As[nb][la1] = va1;  *(uint4*)&As[nb][la2] = va2;
            *(uint4*)&Bs[nb][la1] = vb1;  *(uint4*)&Bs[nb][la2] = vb2;
            buf = nb;
        }
    }
    // epilogue: C/D layout col=lane&15, row=(lane>>4)*4+reg
#pragma unroll
    for (int j = 0; j < 4; ++j) {
        int col = col0 + wc * 64 + j * 16 + l15;
        float bj = bias[col];
#pragma unroll
        for (int i = 0; i < 4; ++i) {
            int rbase = row0 + wr * 64 + i * 16 + kq * 4;
            floatx4 v = acc[i][j];
#pragma unroll
            for (int r = 0; r < 4; ++r) {
                int row = rbase + r;
                if (row < N_NODES) C[(size_t)row * 1024 + col] = pk1(v[r] + bj);
            }
        }
    }
}

// ---------------- fused GATv2 node kernel (r8 template: flat softmax, unroll-2) ----------------
template <int O>
__global__ __launch_bounds__(256, 4) void gat_node_kernel(
    const unsigned short* __restrict__ xl_, const unsigned short* __restrict__ xr_,
    int stride,
    const int* __restrict__ rowptr, const int* __restrict__ col,
    const float* __restrict__ att, const float* __restrict__ bias,
    const float* __restrict__ bng, const float* __restrict__ bnb,
    const float* __restrict__ bnm, const float* __restrict__ bnv,
    unsigned short* __restrict__ out_) {
    constexpr int VE = O / 16;      // bf16 elems per lane (4 or 8)
    constexpr int NW = VE / 2;      // uint words per lane
    constexpr int HO = 4 * O;
    const int wave = threadIdx.x >> 6;
    const int node = blockIdx.x * 4 + wave;
    if (node >= N_NODES) return;
    const int lane = threadIdx.x & 63;
    const int l16 = lane & 15;
    const int cbase = (lane >> 4) * O + l16 * VE;

    float xrv[VE], a06[VE], a04[VE], acc[VE];
    float xvA[VE], xvB[VE];
    {
        unsigned wr_[NW];
        ldrow<NW>(xr_ + (size_t)node * stride + cbase, wr_);
        unpk<NW>(wr_, xrv);
#pragma unroll
        for (int v = 0; v < VE; v += 4) {
            float4 b = *(const float4*)(att + cbase + v);
            a06[v] = 0.6f * b.x; a06[v + 1] = 0.6f * b.y;
            a06[v + 2] = 0.6f * b.z; a06[v + 3] = 0.6f * b.w;
            a04[v] = 0.4f * b.x; a04[v + 1] = 0.4f * b.y;
            a04[v + 2] = 0.4f * b.z; a04[v + 3] = 0.4f * b.w;
        }
    }
    // self-loop edge (src == node)
    float s;
    {
        unsigned ws_[NW];
        ldrow<NW>(xl_ + (size_t)node * stride + cbase, ws_);
        float q = edge_logit<VE, NW>(ws_, xrv, a06, a04, xvA);
#pragma unroll
        for (int d = 1; d < 16; d <<= 1) q += __shfl_xor(q, d, 64);
        float w0 = __expf(q);
        s = w0;
#pragma unroll
        for (int j = 0; j < VE; ++j) acc[j] = w0 * xvA[j];
    }

    int e = rowptr[node];
    const int e1 = rowptr[node + 1];
    const int elast = e1 - 1;
    unsigned nA[NW], nB[NW];
    if (e < e1) ldrow<NW>(xl_ + (size_t)col[e] * stride + cbase, nA);
    if (e + 1 < e1) ldrow<NW>(xl_ + (size_t)col[e + 1] * stride + cbase, nB);
    while (e + 1 < e1) {
        unsigned cA[NW], cB[NW];
#pragma unroll
        for (int i = 0; i < NW; ++i) { cA[i] = nA[i]; cB[i] = nB[i]; }
        int i2 = e + 2 < elast ? e + 2 : elast;
        int i3 = e + 3 < elast ? e + 3 : elast;
        ldrow<NW>(xl_ + (size_t)col[i2] * stride + cbase, nA);
        ldrow<NW>(xl_ + (size_t)col[i3] * stride + cbase, nB);
        e += 2;
        float q1 = edge_logit<VE, NW>(cA, xrv, a06, a04, xvA);
        float q2 = edge_logit<VE, NW>(cB, xrv, a06, a04, xvB);
#pragma unroll
        for (int d = 1; d < 16; d <<= 1) {
            q1 += __shfl_xor(q1, d, 64);
            q2 += __shfl_xor(q2, d, 64);
        }
        float w1 = __expf(q1), w2 = __expf(q2);
        s += w1 + w2;
#pragma unroll
        for (int j = 0; j < VE; ++j)
            acc[j] = fmaf(w1, xvA[j], fmaf(w2, xvB[j], acc[j]));
    }
    if (e < e1) {   // odd tail (row already in nA)
        float q = edge_logit<VE, NW>(nA, xrv, a06, a04, xvA);
#pragma unroll
        for (int d = 1; d < 16; d <<= 1) q += __shfl_xor(q, d, 64);
        float we = __expf(q);
        s += we;
#pragma unroll
        for (int j = 0; j < VE; ++j) acc[j] = fmaf(we, xvA[j], acc[j]);
    }
    float r = 1.f / (s + 1e-16f);
#pragma unroll
    for (int v = 0; v < VE; v += 4) {
        float t[4];
#pragma unroll
        for (int j = 0; j < 4; ++j) {
            int c = cbase + v + j;
            float val = acc[v + j] * r + bias[c];
            float y = bng[c] * (val - bnm[c]) * rsqrtf(bnv[c] + 1e-5f) + bnb[c];
            t[j] = fmaxf(y, 0.f);
        }
        uint2 qo;
        qo.x = pk_bf16(t[0], t[1]);
        qo.y = pk_bf16(t[2], t[3]);
        *(uint2*)(out_ + (size_t)node * HO + cbase + v) = qo;
    }
}

// ---------------- graph boundaries (batch sorted) ----------------
__global__ void gstart_kernel(const int* __restrict__ batch, int* __restrict__ gs) {
    int t = blockIdx.x * blockDim.x + threadIdx.x;
    if (t > N_GRAPHS) return;
    if (t == N_GRAPHS) { gs[N_GRAPHS] = N_NODES; return; }
    int lo = 0, hi = N_NODES;
    while (lo < hi) {
        int mid = (lo + hi) >> 1;
        if (batch[mid] < t) lo = mid + 1; else hi = mid;
    }
    gs[t] = lo;
}

// ---------------- mean pool (h2 bf16 -> pooled fp32), 4 blocks per graph ----------------
__global__ __launch_bounds__(128) void pool_kernel(const unsigned short* __restrict__ h2,
                                                   const int* __restrict__ gs,
                                                   float* __restrict__ pooled) {
    const int g = blockIdx.x >> 2;
    const int quarter = blockIdx.x & 3;
    const int t = threadIdx.x;
    const int c = quarter * 128 + t;
    const int s = gs[g], e = gs[g + 1];
    float a = 0.f;
    for (int r = s; r < e; ++r)
        a += __uint_as_float((unsigned)h2[(size_t)r * HO2 + c] << 16);
    float inv = 1.f / fmaxf((float)(e - s), 1.f);
    pooled[(size_t)g * HO2 + c] = a * inv;
}

// ---------------- MLP head ----------------
__global__ __launch_bounds__(128) void mlp_kernel(const float* __restrict__ pooled,
                                                  const float* __restrict__ gf,
                                                  const float* __restrict__ fc1w,
                                                  const float* __restrict__ fc1b,
                                                  const float* __restrict__ fc2w,
                                                  const float* __restrict__ fc2b,
                                                  float* __restrict__ out) {
    __shared__ float z[704];
    __shared__ float red[2];
    const int g = blockIdx.x, t = threadIdx.x;
    for (int i = t; i < HO2; i += 128) z[i] = pooled[(size_t)g * HO2 + i];
    for (int i = t; i < GF_DIM; i += 128) z[HO2 + i] = gf[(size_t)g * GF_DIM + i];
    __syncthreads();
    float s = fc1b[t];
    for (int k = 0; k < Z_DIM; ++k) s += z[k] * fc1w[k * FC1_DIM + t];
    s = fmaxf(s, 0.f);              // relu (dropout = identity in eval)
    float c = s * fc2w[t];
#pragma unroll
    for (int d = 1; d < 64; d <<= 1) c += __shfl_xor(c, d, 64);
    if ((t & 63) == 0) red[t >> 6] = c;
    __syncthreads();
    if (t == 0) out[g] = red[0] + red[1] + fc2b[0];
}

// ---------------- launch ----------------
extern "C" void kernel_launch(void* const* d_in, const int* in_sizes, int n_in,
                              void* d_out, int out_size, void* d_ws, size_t ws_size,
                              hipStream_t stream) {
    float* out = (float*)d_out;
    if (ws_size < WS_REQUIRED) {
        diag_kernel<<<1, 256, 0, stream>>>(out, (float)(ws_size >> 20));
        return;
    }
    const float* x     = (const float*)d_in[0];
    const int*   ei    = (const int*)d_in[1];
    const int*   batch = (const int*)d_in[2];
    const float* gf    = (const float*)d_in[3];
    const float* Wl1   = (const float*)d_in[4];
    const float* bl1   = (const float*)d_in[5];
    const float* Wr1   = (const float*)d_in[6];
    const float* br1   = (const float*)d_in[7];
    const float* att1  = (const float*)d_in[8];
    const float* bias1 = (const float*)d_in[9];
    const float* bn1g  = (const float*)d_in[10];
    const float* bn1b  = (const float*)d_in[11];
    const float* bn1m  = (const float*)d_in[12];
    const float* bn1v  = (const float*)d_in[13];
    const float* Wl2   = (const float*)d_in[14];
    const float* bl2   = (const float*)d_in[15];
    const float* Wr2   = (const float*)d_in[16];
    const float* br2   = (const float*)d_in[17];
    const float* att2  = (const float*)d_in[18];
    const float* bias2 = (const float*)d_in[19];
    const float* bn2g  = (const float*)d_in[20];
    const float* bn2b  = (const float*)d_in[21];
    const float* bn2m  = (const float*)d_in[22];
    const float* bn2v  = (const float*)d_in[23];
    const float* fc1w  = (const float*)d_in[24];
    const float* fc1b  = (const float*)d_in[25];
    const float* fc2w  = (const float*)d_in[26];
    const float* fc2b  = (const float*)d_in[27];
    char* ws = (char*)d_ws;

    unsigned short* xl1  = (unsigned short*)(ws + OFF_XL1);
    unsigned short* xr1  = (unsigned short*)(ws + OFF_XR1);
    unsigned short* xlr2 = (unsigned short*)(ws + OFF_XLR2);
    unsigned short* h1   = (unsigned short*)(ws + OFF_H1);
    unsigned short* h2   = (unsigned short*)(ws + OFF_H2);
    int* deg     = (int*)(ws + OFF_DEG);
    int* rowptr  = (int*)(ws + OFF_ROWPTR);
    int* cursor  = (int*)(ws + OFF_CURSOR);
    int* col     = (int*)(ws + OFF_COL);
    int* gs      = (int*)(ws + OFF_GS);
    float* pooled= (float*)(ws + OFF_POOLED);
    unsigned short* Wt = (unsigned short*)(ws + OFF_WCAT);
    float* bcat  = (float*)(ws + OFF_BCAT);

    // CSR by destination (self-loops handled in-register by gat kernel)
    zero_deg_kernel<<<(N_NODES + 255) / 256, 256, 0, stream>>>(deg);
    count_kernel<<<(N_EDGES + 255) / 256, 256, 0, stream>>>(ei, deg);
    scan_kernel<<<1, 1024, 0, stream>>>(deg, rowptr, cursor);
    fill_kernel<<<(N_EDGES + 255) / 256, 256, 0, stream>>>(ei, cursor, col);
    gstart_kernel<<<1, 512, 0, stream>>>(batch, gs);

    // layer 1 (bf16 storage, fp32 accumulation)
    mm1_kernel<<<N_NODES / 8, 256, 0, stream>>>(x, Wl1, bl1, Wr1, br1, xl1, xr1);
    gat_node_kernel<64><<<(N_NODES + 3) / 4, 256, 0, stream>>>(
        xl1, xr1, HO1, rowptr, col, att1, bias1, bn1g, bn1b, bn1m, bn1v, h1);

    // layer 2 (bf16 MFMA GEMM, double-buffered + bf16 gather)
    pack_w2_kernel<<<1024, 256, 0, stream>>>(Wl2, Wr2, bl2, br2, Wt, bcat);
    mm2_mfma_kernel<<<dim3(8, (N_NODES + 127) / 128), 256, 0, stream>>>(h1, Wt, bcat, xlr2);
    gat_node_kernel<128><<<(N_NODES + 3) / 4, 256, 0, stream>>>(
        xlr2, xlr2 + HO2, 1024, rowptr, col, att2, bias2, bn2g, bn2b, bn2m, bn2v, h2);

    // pool + head
    pool_kernel<<<N_GRAPHS * 4, 128, 0, stream>>>(h2, gs, pooled);
    mlp_kernel<<<N_GRAPHS, 128, 0, stream>>>(pooled, gf, fc1w, fc1b, fc2w, fc2b, out);
}

// Round 11
// 732.129 us; speedup vs baseline: 1.0645x; 1.0078x over previous
//
#include <hip/hip_runtime.h>

#define N_NODES 50000
#define N_EDGES 800000
#define N_GRAPHS 256
#define F_IN 9
#define GF_DIM 187
#define HO1 256
#define HO2 512
#define FC1_DIM 128
#define Z_DIM (HO2 + GF_DIM)   // 699

// ---------------- workspace layout (bytes) — proven footprint ----------------
#define OFF_XL1   0UL
#define OFF_XR1   25600000UL
#define OFF_XLR2  0UL
#define OFF_H1    102400000UL
#define OFF_H2    102400000UL
#define OFF_SMALL 153600000UL
#define OFF_DEG    (OFF_SMALL + 0UL)
#define OFF_ROWPTR (OFF_SMALL + 200704UL)
#define OFF_CURSOR (OFF_SMALL + 401408UL)
#define OFF_COL    (OFF_SMALL + 602112UL)
#define OFF_GS     (OFF_SMALL + 3802112UL)
#define OFF_POOLED (OFF_SMALL + 3806208UL)   // 512 KB fp32 pooled
#define OFF_WCAT   (OFF_SMALL + 4330496UL)
#define OFF_BCAT   (OFF_SMALL + 5379072UL)
#define WS_REQUIRED (OFF_SMALL + 5383168UL)   // 158,983,168 (proven)

typedef __attribute__((ext_vector_type(8))) short short8;
typedef __attribute__((ext_vector_type(4))) float floatx4;

// ---------------- bf16 helpers (RTNE) ----------------
__device__ __forceinline__ unsigned short pk1(float a) {
    unsigned u = __float_as_uint(a);
    return (unsigned short)((u + 0x7fffu + ((u >> 16) & 1u)) >> 16);
}
__device__ __forceinline__ unsigned pk_bf16(float a, float b) {
    unsigned ua = __float_as_uint(a), ub = __float_as_uint(b);
    ua = (ua + 0x7fffu + ((ua >> 16) & 1u)) >> 16;
    ub = (ub + 0x7fffu + ((ub >> 16) & 1u)) & 0xffff0000u;
    return ua | ub;
}

template <int NW>
__device__ __forceinline__ void ldrow(const unsigned short* p, unsigned* w) {
    if constexpr (NW == 2) *(uint2*)w = *(const uint2*)p;
    else                   *(uint4*)w = *(const uint4*)p;
}
template <int NW>
__device__ __forceinline__ void unpk(const unsigned* w, float* f) {
#pragma unroll
    for (int i = 0; i < NW; ++i) {
        f[2 * i]     = __uint_as_float(w[i] << 16);
        f[2 * i + 1] = __uint_as_float(w[i] & 0xffff0000u);
    }
}

// unpack row + factored-leakyrelu logit partial: q = sum(a06*v + a04*|v|)
template <int VE, int NW>
__device__ __forceinline__ float edge_logit(const unsigned* w, const float* xrv,
                                            const float* a06, const float* a04,
                                            float* xv) {
    unpk<NW>(w, xv);
    float qa = 0.f, qb = 0.f;
#pragma unroll
    for (int j = 0; j < VE; ++j) {
        float v = xv[j] + xrv[j];
        qa = fmaf(a06[j], v, qa);
        qb = fmaf(a04[j], fabsf(v), qb);
    }
    return qa + qb;
}

// ---------------- diagnostic fallback (ws too small) ----------------
__global__ void diag_kernel(float* out, float v) { out[threadIdx.x] = v; }

// ---------------- CSR build ----------------
__global__ __launch_bounds__(256) void zero_deg_kernel(int* __restrict__ deg) {
    int i = blockIdx.x * 256 + threadIdx.x;
    if (i < N_NODES) deg[i] = 0;
}

__global__ __launch_bounds__(256) void count_kernel(const int* __restrict__ ei,
                                                    int* __restrict__ deg) {
    int e = blockIdx.x * 256 + threadIdx.x;
    if (e < N_EDGES) atomicAdd(&deg[ei[N_EDGES + e]], 1);
}

__global__ __launch_bounds__(1024) void scan_kernel(const int* __restrict__ deg,
                                                    int* __restrict__ rowptr,
                                                    int* __restrict__ cursor) {
    __shared__ int part[1024];
    const int t = threadIdx.x;
    const int CH = (N_NODES + 1023) / 1024;   // 49
    int lo = t * CH;
    int hi = lo + CH; if (hi > N_NODES) hi = N_NODES;
    int s = 0;
    for (int i = lo; i < hi; ++i) s += deg[i];
    part[t] = s;
    __syncthreads();
    for (int off = 1; off < 1024; off <<= 1) {
        int v = (t >= off) ? part[t - off] : 0;
        __syncthreads();
        part[t] += v;
        __syncthreads();
    }
    int run = part[t] - s;  // exclusive base
    for (int i = lo; i < hi; ++i) {
        int d = deg[i];
        rowptr[i] = run;
        cursor[i] = run;
        run += d;
    }
    if (t == 1023) rowptr[N_NODES] = part[1023];
}

__global__ __launch_bounds__(256) void fill_kernel(const int* __restrict__ ei,
                                                   int* __restrict__ cursor,
                                                   int* __restrict__ col) {
    int e = blockIdx.x * 256 + threadIdx.x;
    if (e < N_EDGES) {
        int d = ei[N_EDGES + e];
        int pos = atomicAdd(&cursor[d], 1);
        col[pos] = ei[e];
    }
}

// ---------------- layer-1 linear (K=9), 8 nodes/block ----------------
__global__ __launch_bounds__(256) void mm1_kernel(const float* __restrict__ x,
                                                  const float* __restrict__ Wl,
                                                  const float* __restrict__ bl,
                                                  const float* __restrict__ Wr,
                                                  const float* __restrict__ br,
                                                  unsigned short* __restrict__ xl,
                                                  unsigned short* __restrict__ xr) {
    __shared__ float xs[8][F_IN];
    const int n0 = blockIdx.x * 8;           // N_NODES divisible by 8
    const int t = threadIdx.x;
    if (t < 8 * F_IN) xs[t / F_IN][t % F_IN] = x[n0 * F_IN + t];
    __syncthreads();
    const float blv = bl[t], brv = br[t];
    float sl[8], sr[8];
#pragma unroll
    for (int i = 0; i < 8; ++i) { sl[i] = blv; sr[i] = brv; }
#pragma unroll
    for (int k = 0; k < F_IN; ++k) {
        float wlk = Wl[k * HO1 + t];
        float wrk = Wr[k * HO1 + t];
#pragma unroll
        for (int i = 0; i < 8; ++i) {
            sl[i] = fmaf(xs[i][k], wlk, sl[i]);
            sr[i] = fmaf(xs[i][k], wrk, sr[i]);
        }
    }
#pragma unroll
    for (int i = 0; i < 8; ++i) {
        xl[(size_t)(n0 + i) * HO1 + t] = pk1(sl[i]);
        xr[(size_t)(n0 + i) * HO1 + t] = pk1(sr[i]);
    }
}

// ---------------- pack Wl2|Wr2 -> Wt bf16 [1024 n][256 k] (transposed) ----------------
__global__ __launch_bounds__(256) void pack_w2_kernel(const float* __restrict__ Wl2,
                                                      const float* __restrict__ Wr2,
                                                      const float* __restrict__ bl2,
                                                      const float* __restrict__ br2,
                                                      unsigned short* __restrict__ Wt,
                                                      float* __restrict__ bcat) {
    int i = blockIdx.x * 256 + threadIdx.x;   // 0 .. 1024*256-1
    int n = i >> 8, k = i & 255;
    float w = (n < HO2) ? Wl2[k * HO2 + n] : Wr2[k * HO2 + (n - HO2)];
    Wt[i] = pk1(w);
    if (i < 1024) bcat[i] = (i < HO2) ? bl2[i] : br2[i - HO2];
}

// ---------------- layer-2 linear: bf16 MFMA, double-buffered LDS pipeline ----------------
#define LP 40
__global__ __launch_bounds__(256) void mm2_mfma_kernel(
    const unsigned short* __restrict__ A,    // h1 bf16 [N,256]
    const unsigned short* __restrict__ Bt,   // Wt bf16 [1024][256]
    const float* __restrict__ bias,          // bcat [1024]
    unsigned short* __restrict__ C) {        // xlr2 bf16 [N,1024]
    __shared__ unsigned short As[2][128 * LP];  // 2 x 10 KB
    __shared__ unsigned short Bs[2][128 * LP];  // 2 x 10 KB
    const int t = threadIdx.x;
    const int lane = t & 63;
    const int w = t >> 6;
    const int wr = w >> 1, wc = w & 1;       // wave quadrant (64x64)
    const int l15 = lane & 15, kq = lane >> 4;
    const int row0 = blockIdx.y * 128;
    const int col0 = blockIdx.x * 128;

    const int c1 = t, c2 = t + 256;
    int ar1 = row0 + (c1 >> 2); ar1 = ar1 < N_NODES ? ar1 : N_NODES - 1;
    int ar2 = row0 + (c2 >> 2); ar2 = ar2 < N_NODES ? ar2 : N_NODES - 1;
    const unsigned short* pa1 = A + (size_t)ar1 * 256 + (c1 & 3) * 8;
    const unsigned short* pa2 = A + (size_t)ar2 * 256 + (c2 & 3) * 8;
    const unsigned short* pb1 = Bt + (size_t)(col0 + (c1 >> 2)) * 256 + (c1 & 3) * 8;
    const unsigned short* pb2 = Bt + (size_t)(col0 + (c2 >> 2)) * 256 + (c2 & 3) * 8;
    const int la1 = (c1 >> 2) * LP + (c1 & 3) * 8;
    const int la2 = (c2 >> 2) * LP + (c2 & 3) * 8;

    uint4 va1, va2, vb1, vb2;
    va1 = *(const uint4*)(pa1);  va2 = *(const uint4*)(pa2);
    vb1 = *(const uint4*)(pb1);  vb2 = *(const uint4*)(pb2);
    *(uint4*)&As[0][la1] = va1;  *(uint4*)&As[0][la2] = va2;
    *(uint4*)&Bs[0][la1] = vb1;  *(uint4*)&Bs[0][la2] = vb2;

    floatx4 acc[4][4] = {};
    int buf = 0;
    for (int k0 = 0; k0 < 256; k0 += 32) {
        __syncthreads();
        const bool more = (k0 + 32 < 256);
        if (more) {
            va1 = *(const uint4*)(pa1 + k0 + 32);
            va2 = *(const uint4*)(pa2 + k0 + 32);
            vb1 = *(const uint4*)(pb1 + k0 + 32);
            vb2 = *(const uint4*)(pb2 + k0 + 32);
        }
        short8 af[4], bf[4];
#pragma unroll
        for (int i = 0; i < 4; ++i)
            af[i] = *(const short8*)&As[buf][(wr * 64 + i * 16 + l15) * LP + kq * 8];
#pragma unroll
        for (int j = 0; j < 4; ++j)
            bf[j] = *(const short8*)&Bs[buf][(wc * 64 + j * 16 + l15) * LP + kq * 8];
#pragma unroll
        for (int i = 0; i < 4; ++i)
#pragma unroll
            for (int j = 0; j < 4; ++j)
                acc[i][j] = __builtin_amdgcn_mfma_f32_16x16x32_bf16(
                    af[i], bf[j], acc[i][j], 0, 0, 0);
        if (more) {
            int nb = 1 - buf;
            *(uint4*)&As[nb][la1] = va1;  *(uint4*)&As[nb][la2] = va2;
            *(uint4*)&Bs[nb][la1] = vb1;  *(uint4*)&Bs[nb][la2] = vb2;
            buf = nb;
        }
    }
#pragma unroll
    for (int j = 0; j < 4; ++j) {
        int col = col0 + wc * 64 + j * 16 + l15;
        float bj = bias[col];
#pragma unroll
        for (int i = 0; i < 4; ++i) {
            int rbase = row0 + wr * 64 + i * 16 + kq * 4;
            floatx4 v = acc[i][j];
#pragma unroll
            for (int r = 0; r < 4; ++r) {
                int row = rbase + r;
                if (row < N_NODES) C[(size_t)row * 1024 + col] = pk1(v[r] + bj);
            }
        }
    }
}

// ---------------- fused GATv2 node kernel ----------------
// GROUPS lane-groups per wave, each processing its own edge stream with
// r8-proven distance-1 prefetch + unroll-2. Each group covers the FULL row
// (GS lanes x VE elems). Clamped indices + zero weights for tails.
template <int O, int GROUPS>
__global__ __launch_bounds__(256, 4) void gat_node_kernel(
    const unsigned short* __restrict__ xl_, const unsigned short* __restrict__ xr_,
    int stride,
    const int* __restrict__ rowptr, const int* __restrict__ col,
    const float* __restrict__ att, const float* __restrict__ bias,
    const float* __restrict__ bng, const float* __restrict__ bnb,
    const float* __restrict__ bnm, const float* __restrict__ bnv,
    unsigned short* __restrict__ out_) {
    constexpr int TOT = 4 * O;        // row length in bf16
    constexpr int GS  = 64 / GROUPS;  // lanes per group
    constexpr int VE  = TOT / GS;     // 8 for both layers
    constexpr int NW  = VE / 2;       // 4 (uint4 loads)
    constexpr int LPH = O / VE;       // lanes per head within group
    const int wave = threadIdx.x >> 6;
    const int node = blockIdx.x * 4 + wave;
    if (node >= N_NODES) return;
    const int lane = threadIdx.x & 63;
    const int gid  = lane / GS;
    const int gl   = lane % GS;
    const int cbase = gl * VE;

    float xrv[VE], a06[VE], a04[VE], acc[VE], xvA[VE], xvB[VE];
    {
        unsigned w_[NW];
        ldrow<NW>(xr_ + (size_t)node * stride + cbase, w_);
        unpk<NW>(w_, xrv);
#pragma unroll
        for (int v = 0; v < VE; v += 4) {
            float4 b = *(const float4*)(att + cbase + v);
            a06[v] = 0.6f * b.x; a06[v + 1] = 0.6f * b.y;
            a06[v + 2] = 0.6f * b.z; a06[v + 3] = 0.6f * b.w;
            a04[v] = 0.4f * b.x; a04[v + 1] = 0.4f * b.y;
            a04[v + 2] = 0.4f * b.z; a04[v + 3] = 0.4f * b.w;
        }
    }
    // self-loop edge (weight counted by group 0 only)
    float s;
    {
        unsigned w_[NW];
        ldrow<NW>(xl_ + (size_t)node * stride + cbase, w_);
        float q = edge_logit<VE, NW>(w_, xrv, a06, a04, xvA);
#pragma unroll
        for (int d = 1; d < LPH; d <<= 1) q += __shfl_xor(q, d, 64);
        float w0 = (GROUPS == 1 || gid == 0) ? __expf(q) : 0.f;
        s = w0;
#pragma unroll
        for (int j = 0; j < VE; ++j) acc[j] = w0 * xvA[j];
    }

    const int e0 = rowptr[node], e1 = rowptr[node + 1];
    const int deg = e1 - e0;
    constexpr int PER = 2 * GROUPS;           // edges per wave-iteration
    const int itc = (deg + PER - 1) / PER;
    const int elast = e1 - 1;
    int ia = e0 + 2 * gid;                    // this group's pair start, iter 0
    unsigned nA[NW], nB[NW];
    if (itc > 0) {
        int a = ia < elast ? ia : elast;
        int b = ia + 1 < elast ? ia + 1 : elast;
        ldrow<NW>(xl_ + (size_t)col[a] * stride + cbase, nA);
        ldrow<NW>(xl_ + (size_t)col[b] * stride + cbase, nB);
    }
    for (int k = 0; k < itc; ++k) {
        unsigned cA[NW], cB[NW];
#pragma unroll
        for (int i = 0; i < NW; ++i) { cA[i] = nA[i]; cB[i] = nB[i]; }
        int inext = ia + PER;
        if (k + 1 < itc) {                    // distance-1 prefetch, clamped
            int a = inext < elast ? inext : elast;
            int b = inext + 1 < elast ? inext + 1 : elast;
            ldrow<NW>(xl_ + (size_t)col[a] * stride + cbase, nA);
            ldrow<NW>(xl_ + (size_t)col[b] * stride + cbase, nB);
        }
        float q1 = edge_logit<VE, NW>(cA, xrv, a06, a04, xvA);
        float q2 = edge_logit<VE, NW>(cB, xrv, a06, a04, xvB);
#pragma unroll
        for (int d = 1; d < LPH; d <<= 1) {
            q1 += __shfl_xor(q1, d, 64);
            q2 += __shfl_xor(q2, d, 64);
        }
        float w1 = (ia < e1) ? __expf(q1) : 0.f;
        float w2 = (ia + 1 < e1) ? __expf(q2) : 0.f;
        s += w1 + w2;
#pragma unroll
        for (int j = 0; j < VE; ++j)
            acc[j] = fmaf(w1, xvA[j], fmaf(w2, xvB[j], acc[j]));
        ia = inext;
    }
    if constexpr (GROUPS == 2) {   // merge group partials (same element space)
        s += __shfl_xor(s, 32, 64);
#pragma unroll
        for (int j = 0; j < VE; ++j) acc[j] += __shfl_xor(acc[j], 32, 64);
    }
    float r = 1.f / (s + 1e-16f);
    if (GROUPS == 1 || gid == 0) {
        float t[VE];
#pragma unroll
        for (int j = 0; j < VE; ++j) {
            int c = cbase + j;
            float val = acc[j] * r + bias[c];
            float y = bng[c] * (val - bnm[c]) * rsqrtf(bnv[c] + 1e-5f) + bnb[c];
            t[j] = fmaxf(y, 0.f);
        }
        uint4 qo;
        qo.x = pk_bf16(t[0], t[1]);
        qo.y = pk_bf16(t[2], t[3]);
        qo.z = pk_bf16(t[4], t[5]);
        qo.w = pk_bf16(t[6], t[7]);
        *(uint4*)(out_ + (size_t)node * TOT + cbase) = qo;
    }
}

// ---------------- graph boundaries (batch sorted) ----------------
__global__ void gstart_kernel(const int* __restrict__ batch, int* __restrict__ gs) {
    int t = blockIdx.x * blockDim.x + threadIdx.x;
    if (t > N_GRAPHS) return;
    if (t == N_GRAPHS) { gs[N_GRAPHS] = N_NODES; return; }
    int lo = 0, hi = N_NODES;
    while (lo < hi) {
        int mid = (lo + hi) >> 1;
        if (batch[mid] < t) lo = mid + 1; else hi = mid;
    }
    gs[t] = lo;
}

// ---------------- mean pool (h2 bf16 -> pooled fp32), vectorized ----------------
__global__ __launch_bounds__(128) void pool_kernel(const unsigned short* __restrict__ h2,
                                                   const int* __restrict__ gs,
                                                   float* __restrict__ pooled) {
    const int g = blockIdx.x;
    const int c4 = threadIdx.x * 4;   // 128 threads x 4 cols = 512
    const int s = gs[g], e = gs[g + 1];
    float a0 = 0.f, a1 = 0.f, a2 = 0.f, a3 = 0.f;
    for (int r = s; r < e; ++r) {
        uint2 q = *(const uint2*)(h2 + (size_t)r * HO2 + c4);
        a0 += __uint_as_float(q.x << 16);
        a1 += __uint_as_float(q.x & 0xffff0000u);
        a2 += __uint_as_float(q.y << 16);
        a3 += __uint_as_float(q.y & 0xffff0000u);
    }
    float inv = 1.f / fmaxf((float)(e - s), 1.f);
    float4 o; o.x = a0 * inv; o.y = a1 * inv; o.z = a2 * inv; o.w = a3 * inv;
    *(float4*)(pooled + (size_t)g * HO2 + c4) = o;
}

// ---------------- MLP head ----------------
__global__ __launch_bounds__(128) void mlp_kernel(const float* __restrict__ pooled,
                                                  const float* __restrict__ gf,
                                                  const float* __restrict__ fc1w,
                                                  const float* __restrict__ fc1b,
                                                  const float* __restrict__ fc2w,
                                                  const float* __restrict__ fc2b,
                                                  float* __restrict__ out) {
    __shared__ float z[704];
    __shared__ float red[2];
    const int g = blockIdx.x, t = threadIdx.x;
    for (int i = t; i < HO2; i += 128) z[i] = pooled[(size_t)g * HO2 + i];
    for (int i = t; i < GF_DIM; i += 128) z[HO2 + i] = gf[(size_t)g * GF_DIM + i];
    __syncthreads();
    float s = fc1b[t];
    for (int k = 0; k < Z_DIM; ++k) s += z[k] * fc1w[k * FC1_DIM + t];
    s = fmaxf(s, 0.f);              // relu (dropout = identity in eval)
    float c = s * fc2w[t];
#pragma unroll
    for (int d = 1; d < 64; d <<= 1) c += __shfl_xor(c, d, 64);
    if ((t & 63) == 0) red[t >> 6] = c;
    __syncthreads();
    if (t == 0) out[g] = red[0] + red[1] + fc2b[0];
}

// ---------------- launch ----------------
extern "C" void kernel_launch(void* const* d_in, const int* in_sizes, int n_in,
                              void* d_out, int out_size, void* d_ws, size_t ws_size,
                              hipStream_t stream) {
    float* out = (float*)d_out;
    if (ws_size < WS_REQUIRED) {
        diag_kernel<<<1, 256, 0, stream>>>(out, (float)(ws_size >> 20));
        return;
    }
    const float* x     = (const float*)d_in[0];
    const int*   ei    = (const int*)d_in[1];
    const int*   batch = (const int*)d_in[2];
    const float* gf    = (const float*)d_in[3];
    const float* Wl1   = (const float*)d_in[4];
    const float* bl1   = (const float*)d_in[5];
    const float* Wr1   = (const float*)d_in[6];
    const float* br1   = (const float*)d_in[7];
    const float* att1  = (const float*)d_in[8];
    const float* bias1 = (const float*)d_in[9];
    const float* bn1g  = (const float*)d_in[10];
    const float* bn1b  = (const float*)d_in[11];
    const float* bn1m  = (const float*)d_in[12];
    const float* bn1v  = (const float*)d_in[13];
    const float* Wl2   = (const float*)d_in[14];
    const float* bl2   = (const float*)d_in[15];
    const float* Wr2   = (const float*)d_in[16];
    const float* br2   = (const float*)d_in[17];
    const float* att2  = (const float*)d_in[18];
    const float* bias2 = (const float*)d_in[19];
    const float* bn2g  = (const float*)d_in[20];
    const float* bn2b  = (const float*)d_in[21];
    const float* bn2m  = (const float*)d_in[22];
    const float* bn2v  = (const float*)d_in[23];
    const float* fc1w  = (const float*)d_in[24];
    const float* fc1b  = (const float*)d_in[25];
    const float* fc2w  = (const float*)d_in[26];
    const float* fc2b  = (const float*)d_in[27];
    char* ws = (char*)d_ws;

    unsigned short* xl1  = (unsigned short*)(ws + OFF_XL1);
    unsigned short* xr1  = (unsigned short*)(ws + OFF_XR1);
    unsigned short* xlr2 = (unsigned short*)(ws + OFF_XLR2);
    unsigned short* h1   = (unsigned short*)(ws + OFF_H1);
    unsigned short* h2   = (unsigned short*)(ws + OFF_H2);
    int* deg     = (int*)(ws + OFF_DEG);
    int* rowptr  = (int*)(ws + OFF_ROWPTR);
    int* cursor  = (int*)(ws + OFF_CURSOR);
    int* col     = (int*)(ws + OFF_COL);
    int* gs      = (int*)(ws + OFF_GS);
    float* pooled= (float*)(ws + OFF_POOLED);
    unsigned short* Wt = (unsigned short*)(ws + OFF_WCAT);
    float* bcat  = (float*)(ws + OFF_BCAT);

    // CSR by destination (self-loops handled in-register by gat kernel)
    zero_deg_kernel<<<(N_NODES + 255) / 256, 256, 0, stream>>>(deg);
    count_kernel<<<(N_EDGES + 255) / 256, 256, 0, stream>>>(ei, deg);
    scan_kernel<<<1, 1024, 0, stream>>>(deg, rowptr, cursor);
    fill_kernel<<<(N_EDGES + 255) / 256, 256, 0, stream>>>(ei, cursor, col);
    gstart_kernel<<<1, 512, 0, stream>>>(batch, gs);

    // layer 1 (bf16 storage, fp32 accumulation); gat1: 4 edges/wave
    mm1_kernel<<<N_NODES / 8, 256, 0, stream>>>(x, Wl1, bl1, Wr1, br1, xl1, xr1);
    gat_node_kernel<64, 2><<<(N_NODES + 3) / 4, 256, 0, stream>>>(
        xl1, xr1, HO1, rowptr, col, att1, bias1, bn1g, bn1b, bn1m, bn1v, h1);

    // layer 2 (bf16 MFMA GEMM, double-buffered + bf16 gather)
    pack_w2_kernel<<<1024, 256, 0, stream>>>(Wl2, Wr2, bl2, br2, Wt, bcat);
    mm2_mfma_kernel<<<dim3(8, (N_NODES + 127) / 128), 256, 0, stream>>>(h1, Wt, bcat, xlr2);
    gat_node_kernel<128, 1><<<(N_NODES + 3) / 4, 256, 0, stream>>>(
        xlr2, xlr2 + HO2, 1024, rowptr, col, att2, bias2, bn2g, bn2b, bn2m, bn2v, h2);

    // pool + head
    pool_kernel<<<N_GRAPHS, 128, 0, stream>>>(h2, gs, pooled);
    mlp_kernel<<<N_GRAPHS, 128, 0, stream>>>(pooled, gf, fc1w, fc1b, fc2w, fc2b, out);
}

// Round 12
// 721.400 us; speedup vs baseline: 1.0803x; 1.0149x over previous
//
#include <hip/hip_runtime.h>

#define N_NODES 50000
#define N_EDGES 800000
#define N_GRAPHS 256
#define F_IN 9
#define GF_DIM 187
#define HO1 256
#define HO2 512
#define FC1_DIM 128
#define Z_DIM (HO2 + GF_DIM)   // 699

// ---------------- workspace layout (bytes) — proven footprint ----------------
#define OFF_XL1   0UL
#define OFF_XR1   25600000UL
#define OFF_XLR2  0UL
#define OFF_H1    102400000UL
#define OFF_H2    102400000UL
#define OFF_SMALL 153600000UL
#define OFF_DEG    (OFF_SMALL + 0UL)
#define OFF_ROWPTR (OFF_SMALL + 200704UL)
#define OFF_CURSOR (OFF_SMALL + 401408UL)
#define OFF_COL    (OFF_SMALL + 602112UL)
#define OFF_GS     (OFF_SMALL + 3802112UL)
#define OFF_POOLED (OFF_SMALL + 3806208UL)   // 512 KB fp32 pooled
#define OFF_WCAT   (OFF_SMALL + 4330496UL)
#define OFF_BCAT   (OFF_SMALL + 5379072UL)
#define WS_REQUIRED (OFF_SMALL + 5383168UL)   // 158,983,168 (proven)

typedef __attribute__((ext_vector_type(8))) short short8;
typedef __attribute__((ext_vector_type(4))) float floatx4;

// ---------------- bf16 helpers (RTNE) ----------------
__device__ __forceinline__ unsigned short pk1(float a) {
    unsigned u = __float_as_uint(a);
    return (unsigned short)((u + 0x7fffu + ((u >> 16) & 1u)) >> 16);
}
__device__ __forceinline__ unsigned pk_bf16(float a, float b) {
    unsigned ua = __float_as_uint(a), ub = __float_as_uint(b);
    ua = (ua + 0x7fffu + ((ua >> 16) & 1u)) >> 16;
    ub = (ub + 0x7fffu + ((ub >> 16) & 1u)) & 0xffff0000u;
    return ua | ub;
}

template <int NW>
__device__ __forceinline__ void ldrow(const unsigned short* p, unsigned* w) {
    if constexpr (NW == 2) *(uint2*)w = *(const uint2*)p;
    else                   *(uint4*)w = *(const uint4*)p;
}
template <int NW>
__device__ __forceinline__ void unpk(const unsigned* w, float* f) {
#pragma unroll
    for (int i = 0; i < NW; ++i) {
        f[2 * i]     = __uint_as_float(w[i] << 16);
        f[2 * i + 1] = __uint_as_float(w[i] & 0xffff0000u);
    }
}

// unpack row + factored-leakyrelu logit partial: q = sum(a06*v + a04*|v|)
template <int VE, int NW>
__device__ __forceinline__ float edge_logit(const unsigned* w, const float* xrv,
                                            const float* a06, const float* a04,
                                            float* xv) {
    unpk<NW>(w, xv);
    float qa = 0.f, qb = 0.f;
#pragma unroll
    for (int j = 0; j < VE; ++j) {
        float v = xv[j] + xrv[j];
        qa = fmaf(a06[j], v, qa);
        qb = fmaf(a04[j], fabsf(v), qb);
    }
    return qa + qb;
}

// ---------------- diagnostic fallback (ws too small) ----------------
__global__ void diag_kernel(float* out, float v) { out[threadIdx.x] = v; }

// ---------------- fused setup: zero deg | graph starts | pack W2 ----------------
// blocks [0,195]: zero deg; block 196: gstart; blocks [197,1220]: pack Wt/bcat
__global__ __launch_bounds__(256) void setup_kernel(int* __restrict__ deg,
                                                    const int* __restrict__ batch,
                                                    int* __restrict__ gs,
                                                    const float* __restrict__ Wl2,
                                                    const float* __restrict__ Wr2,
                                                    const float* __restrict__ bl2,
                                                    const float* __restrict__ br2,
                                                    unsigned short* __restrict__ Wt,
                                                    float* __restrict__ bcat) {
    const int b = blockIdx.x, t = threadIdx.x;
    if (b < 196) {
        int i = b * 256 + t;
        if (i < N_NODES) deg[i] = 0;
    } else if (b == 196) {
        // binary search graph boundaries (batch sorted); t = graph id
        int lo = 0, hi = N_NODES;
        while (lo < hi) {
            int mid = (lo + hi) >> 1;
            if (batch[mid] < t) lo = mid + 1; else hi = mid;
        }
        gs[t] = lo;
        if (t == 0) gs[N_GRAPHS] = N_NODES;
    } else {
        int i = (b - 197) * 256 + t;          // 0 .. 1024*256-1
        int n = i >> 8, k = i & 255;
        float w = (n < HO2) ? Wl2[k * HO2 + n] : Wr2[k * HO2 + (n - HO2)];
        Wt[i] = pk1(w);
        if (i < 1024) bcat[i] = (i < HO2) ? bl2[i] : br2[i - HO2];
    }
}

// ---------------- CSR build ----------------
__global__ __launch_bounds__(256) void count_kernel(const int* __restrict__ ei,
                                                    int* __restrict__ deg) {
    int e = blockIdx.x * 256 + threadIdx.x;
    if (e < N_EDGES) atomicAdd(&deg[ei[N_EDGES + e]], 1);
}

__global__ __launch_bounds__(1024) void scan_kernel(const int* __restrict__ deg,
                                                    int* __restrict__ rowptr,
                                                    int* __restrict__ cursor) {
    __shared__ int part[1024];
    const int t = threadIdx.x;
    const int CH = (N_NODES + 1023) / 1024;   // 49
    int lo = t * CH;
    int hi = lo + CH; if (hi > N_NODES) hi = N_NODES;
    int s = 0;
    for (int i = lo; i < hi; ++i) s += deg[i];
    part[t] = s;
    __syncthreads();
    for (int off = 1; off < 1024; off <<= 1) {
        int v = (t >= off) ? part[t - off] : 0;
        __syncthreads();
        part[t] += v;
        __syncthreads();
    }
    int run = part[t] - s;  // exclusive base
    for (int i = lo; i < hi; ++i) {
        int d = deg[i];
        rowptr[i] = run;
        cursor[i] = run;
        run += d;
    }
    if (t == 1023) rowptr[N_NODES] = part[1023];
}

__global__ __launch_bounds__(256) void fill_kernel(const int* __restrict__ ei,
                                                   int* __restrict__ cursor,
                                                   int* __restrict__ col) {
    int e = blockIdx.x * 256 + threadIdx.x;
    if (e < N_EDGES) {
        int d = ei[N_EDGES + e];
        int pos = atomicAdd(&cursor[d], 1);
        col[pos] = ei[e];
    }
}

// ---------------- layer-1 linear (K=9), 8 nodes/block ----------------
__global__ __launch_bounds__(256) void mm1_kernel(const float* __restrict__ x,
                                                  const float* __restrict__ Wl,
                                                  const float* __restrict__ bl,
                                                  const float* __restrict__ Wr,
                                                  const float* __restrict__ br,
                                                  unsigned short* __restrict__ xl,
                                                  unsigned short* __restrict__ xr) {
    __shared__ float xs[8][F_IN];
    const int n0 = blockIdx.x * 8;           // N_NODES divisible by 8
    const int t = threadIdx.x;
    if (t < 8 * F_IN) xs[t / F_IN][t % F_IN] = x[n0 * F_IN + t];
    __syncthreads();
    const float blv = bl[t], brv = br[t];
    float sl[8], sr[8];
#pragma unroll
    for (int i = 0; i < 8; ++i) { sl[i] = blv; sr[i] = brv; }
#pragma unroll
    for (int k = 0; k < F_IN; ++k) {
        float wlk = Wl[k * HO1 + t];
        float wrk = Wr[k * HO1 + t];
#pragma unroll
        for (int i = 0; i < 8; ++i) {
            sl[i] = fmaf(xs[i][k], wlk, sl[i]);
            sr[i] = fmaf(xs[i][k], wrk, sr[i]);
        }
    }
#pragma unroll
    for (int i = 0; i < 8; ++i) {
        xl[(size_t)(n0 + i) * HO1 + t] = pk1(sl[i]);
        xr[(size_t)(n0 + i) * HO1 + t] = pk1(sr[i]);
    }
}

// ---------------- layer-2 linear: bf16 MFMA, double-buffered LDS pipeline ----------------
#define LP 40
__global__ __launch_bounds__(256) void mm2_mfma_kernel(
    const unsigned short* __restrict__ A,    // h1 bf16 [N,256]
    const unsigned short* __restrict__ Bt,   // Wt bf16 [1024][256]
    const float* __restrict__ bias,          // bcat [1024]
    unsigned short* __restrict__ C) {        // xlr2 bf16 [N,1024]
    __shared__ unsigned short As[2][128 * LP];  // 2 x 10 KB
    __shared__ unsigned short Bs[2][128 * LP];  // 2 x 10 KB
    const int t = threadIdx.x;
    const int lane = t & 63;
    const int w = t >> 6;
    const int wr = w >> 1, wc = w & 1;       // wave quadrant (64x64)
    const int l15 = lane & 15, kq = lane >> 4;
    const int row0 = blockIdx.y * 128;
    const int col0 = blockIdx.x * 128;

    const int c1 = t, c2 = t + 256;
    int ar1 = row0 + (c1 >> 2); ar1 = ar1 < N_NODES ? ar1 : N_NODES - 1;
    int ar2 = row0 + (c2 >> 2); ar2 = ar2 < N_NODES ? ar2 : N_NODES - 1;
    const unsigned short* pa1 = A + (size_t)ar1 * 256 + (c1 & 3) * 8;
    const unsigned short* pa2 = A + (size_t)ar2 * 256 + (c2 & 3) * 8;
    const unsigned short* pb1 = Bt + (size_t)(col0 + (c1 >> 2)) * 256 + (c1 & 3) * 8;
    const unsigned short* pb2 = Bt + (size_t)(col0 + (c2 >> 2)) * 256 + (c2 & 3) * 8;
    const int la1 = (c1 >> 2) * LP + (c1 & 3) * 8;
    const int la2 = (c2 >> 2) * LP + (c2 & 3) * 8;

    uint4 va1, va2, vb1, vb2;
    va1 = *(const uint4*)(pa1);  va2 = *(const uint4*)(pa2);
    vb1 = *(const uint4*)(pb1);  vb2 = *(const uint4*)(pb2);
    *(uint4*)&As[0][la1] = va1;  *(uint4*)&As[0][la2] = va2;
    *(uint4*)&Bs[0][la1] = vb1;  *(uint4*)&Bs[0][la2] = vb2;

    floatx4 acc[4][4] = {};
    int buf = 0;
    for (int k0 = 0; k0 < 256; k0 += 32) {
        __syncthreads();
        const bool more = (k0 + 32 < 256);
        if (more) {
            va1 = *(const uint4*)(pa1 + k0 + 32);
            va2 = *(const uint4*)(pa2 + k0 + 32);
            vb1 = *(const uint4*)(pb1 + k0 + 32);
            vb2 = *(const uint4*)(pb2 + k0 + 32);
        }
        short8 af[4], bf[4];
#pragma unroll
        for (int i = 0; i < 4; ++i)
            af[i] = *(const short8*)&As[buf][(wr * 64 + i * 16 + l15) * LP + kq * 8];
#pragma unroll
        for (int j = 0; j < 4; ++j)
            bf[j] = *(const short8*)&Bs[buf][(wc * 64 + j * 16 + l15) * LP + kq * 8];
#pragma unroll
        for (int i = 0; i < 4; ++i)
#pragma unroll
            for (int j = 0; j < 4; ++j)
                acc[i][j] = __builtin_amdgcn_mfma_f32_16x16x32_bf16(
                    af[i], bf[j], acc[i][j], 0, 0, 0);
        if (more) {
            int nb = 1 - buf;
            *(uint4*)&As[nb][la1] = va1;  *(uint4*)&As[nb][la2] = va2;
            *(uint4*)&Bs[nb][la1] = vb1;  *(uint4*)&Bs[nb][la2] = vb2;
            buf = nb;
        }
    }
#pragma unroll
    for (int j = 0; j < 4; ++j) {
        int col = col0 + wc * 64 + j * 16 + l15;
        float bj = bias[col];
#pragma unroll
        for (int i = 0; i < 4; ++i) {
            int rbase = row0 + wr * 64 + i * 16 + kq * 4;
            floatx4 v = acc[i][j];
#pragma unroll
            for (int r = 0; r < 4; ++r) {
                int row = rbase + r;
                if (row < N_NODES) C[(size_t)row * 1024 + col] = pk1(v[r] + bj);
            }
        }
    }
}

// ---------------- gat1: GROUPS=2 lane-split kernel (r11, proven for layer 1) ----------------
template <int O, int GROUPS>
__global__ __launch_bounds__(256, 4) void gat_node_kernel(
    const unsigned short* __restrict__ xl_, const unsigned short* __restrict__ xr_,
    int stride,
    const int* __restrict__ rowptr, const int* __restrict__ col,
    const float* __restrict__ att, const float* __restrict__ bias,
    const float* __restrict__ bng, const float* __restrict__ bnb,
    const float* __restrict__ bnm, const float* __restrict__ bnv,
    unsigned short* __restrict__ out_) {
    constexpr int TOT = 4 * O;
    constexpr int GS  = 64 / GROUPS;
    constexpr int VE  = TOT / GS;     // 8
    constexpr int NW  = VE / 2;       // 4
    constexpr int LPH = O / VE;
    const int wave = threadIdx.x >> 6;
    const int node = blockIdx.x * 4 + wave;
    if (node >= N_NODES) return;
    const int lane = threadIdx.x & 63;
    const int gid  = lane / GS;
    const int gl   = lane % GS;
    const int cbase = gl * VE;

    float xrv[VE], a06[VE], a04[VE], acc[VE], xvA[VE], xvB[VE];
    {
        unsigned w_[NW];
        ldrow<NW>(xr_ + (size_t)node * stride + cbase, w_);
        unpk<NW>(w_, xrv);
#pragma unroll
        for (int v = 0; v < VE; v += 4) {
            float4 b = *(const float4*)(att + cbase + v);
            a06[v] = 0.6f * b.x; a06[v + 1] = 0.6f * b.y;
            a06[v + 2] = 0.6f * b.z; a06[v + 3] = 0.6f * b.w;
            a04[v] = 0.4f * b.x; a04[v + 1] = 0.4f * b.y;
            a04[v + 2] = 0.4f * b.z; a04[v + 3] = 0.4f * b.w;
        }
    }
    float s;
    {
        unsigned w_[NW];
        ldrow<NW>(xl_ + (size_t)node * stride + cbase, w_);
        float q = edge_logit<VE, NW>(w_, xrv, a06, a04, xvA);
#pragma unroll
        for (int d = 1; d < LPH; d <<= 1) q += __shfl_xor(q, d, 64);
        float w0 = (GROUPS == 1 || gid == 0) ? __expf(q) : 0.f;
        s = w0;
#pragma unroll
        for (int j = 0; j < VE; ++j) acc[j] = w0 * xvA[j];
    }

    const int e0 = rowptr[node], e1 = rowptr[node + 1];
    const int deg = e1 - e0;
    constexpr int PER = 2 * GROUPS;
    const int itc = (deg + PER - 1) / PER;
    const int elast = e1 - 1;
    int ia = e0 + 2 * gid;
    unsigned nA[NW], nB[NW];
    if (itc > 0) {
        int a = ia < elast ? ia : elast;
        int b = ia + 1 < elast ? ia + 1 : elast;
        ldrow<NW>(xl_ + (size_t)col[a] * stride + cbase, nA);
        ldrow<NW>(xl_ + (size_t)col[b] * stride + cbase, nB);
    }
    for (int k = 0; k < itc; ++k) {
        unsigned cA[NW], cB[NW];
#pragma unroll
        for (int i = 0; i < NW; ++i) { cA[i] = nA[i]; cB[i] = nB[i]; }
        int inext = ia + PER;
        if (k + 1 < itc) {
            int a = inext < elast ? inext : elast;
            int b = inext + 1 < elast ? inext + 1 : elast;
            ldrow<NW>(xl_ + (size_t)col[a] * stride + cbase, nA);
            ldrow<NW>(xl_ + (size_t)col[b] * stride + cbase, nB);
        }
        float q1 = edge_logit<VE, NW>(cA, xrv, a06, a04, xvA);
        float q2 = edge_logit<VE, NW>(cB, xrv, a06, a04, xvB);
#pragma unroll
        for (int d = 1; d < LPH; d <<= 1) {
            q1 += __shfl_xor(q1, d, 64);
            q2 += __shfl_xor(q2, d, 64);
        }
        float w1 = (ia < e1) ? __expf(q1) : 0.f;
        float w2 = (ia + 1 < e1) ? __expf(q2) : 0.f;
        s += w1 + w2;
#pragma unroll
        for (int j = 0; j < VE; ++j)
            acc[j] = fmaf(w1, xvA[j], fmaf(w2, xvB[j], acc[j]));
        ia = inext;
    }
    if constexpr (GROUPS == 2) {
        s += __shfl_xor(s, 32, 64);
#pragma unroll
        for (int j = 0; j < VE; ++j) acc[j] += __shfl_xor(acc[j], 32, 64);
    }
    float r = 1.f / (s + 1e-16f);
    if (GROUPS == 1 || gid == 0) {
        float t[VE];
#pragma unroll
        for (int j = 0; j < VE; ++j) {
            int c = cbase + j;
            float val = acc[j] * r + bias[c];
            float y = bng[c] * (val - bnm[c]) * rsqrtf(bnv[c] + 1e-5f) + bnb[c];
            t[j] = fmaxf(y, 0.f);
        }
        uint4 qo;
        qo.x = pk_bf16(t[0], t[1]);
        qo.y = pk_bf16(t[2], t[3]);
        qo.z = pk_bf16(t[4], t[5]);
        qo.w = pk_bf16(t[6], t[7]);
        *(uint4*)(out_ + (size_t)node * TOT + cbase) = qo;
    }
}

// ---------------- gat2: r8-exact kernel (proven 128.7 us, VGPR 40) ----------------
template <int O>
__global__ __launch_bounds__(256, 4) void gat2_kernel(
    const unsigned short* __restrict__ xl_, const unsigned short* __restrict__ xr_,
    int stride,
    const int* __restrict__ rowptr, const int* __restrict__ col,
    const float* __restrict__ att, const float* __restrict__ bias,
    const float* __restrict__ bng, const float* __restrict__ bnb,
    const float* __restrict__ bnm, const float* __restrict__ bnv,
    unsigned short* __restrict__ out_) {
    constexpr int VE = O / 16;
    constexpr int NW = VE / 2;
    constexpr int HO = 4 * O;
    const int wave = threadIdx.x >> 6;
    const int node = blockIdx.x * 4 + wave;
    if (node >= N_NODES) return;
    const int lane = threadIdx.x & 63;
    const int l16 = lane & 15;
    const int cbase = (lane >> 4) * O + l16 * VE;

    float xrv[VE], a06[VE], a04[VE], acc[VE];
    float xvA[VE], xvB[VE];
    {
        unsigned wr_[NW];
        ldrow<NW>(xr_ + (size_t)node * stride + cbase, wr_);
        unpk<NW>(wr_, xrv);
#pragma unroll
        for (int v = 0; v < VE; v += 4) {
            float4 b = *(const float4*)(att + cbase + v);
            a06[v] = 0.6f * b.x; a06[v + 1] = 0.6f * b.y;
            a06[v + 2] = 0.6f * b.z; a06[v + 3] = 0.6f * b.w;
            a04[v] = 0.4f * b.x; a04[v + 1] = 0.4f * b.y;
            a04[v + 2] = 0.4f * b.z; a04[v + 3] = 0.4f * b.w;
        }
    }
    float s;
    {
        unsigned ws_[NW];
        ldrow<NW>(xl_ + (size_t)node * stride + cbase, ws_);
        float q = edge_logit<VE, NW>(ws_, xrv, a06, a04, xvA);
#pragma unroll
        for (int d = 1; d < 16; d <<= 1) q += __shfl_xor(q, d, 64);
        float w0 = __expf(q);
        s = w0;
#pragma unroll
        for (int j = 0; j < VE; ++j) acc[j] = w0 * xvA[j];
    }

    int e = rowptr[node];
    const int e1 = rowptr[node + 1];
    const int elast = e1 - 1;
    unsigned nA[NW], nB[NW];
    if (e < e1) ldrow<NW>(xl_ + (size_t)col[e] * stride + cbase, nA);
    if (e + 1 < e1) ldrow<NW>(xl_ + (size_t)col[e + 1] * stride + cbase, nB);
    while (e + 1 < e1) {
        unsigned cA[NW], cB[NW];
#pragma unroll
        for (int i = 0; i < NW; ++i) { cA[i] = nA[i]; cB[i] = nB[i]; }
        int i2 = e + 2 < elast ? e + 2 : elast;
        int i3 = e + 3 < elast ? e + 3 : elast;
        ldrow<NW>(xl_ + (size_t)col[i2] * stride + cbase, nA);
        ldrow<NW>(xl_ + (size_t)col[i3] * stride + cbase, nB);
        e += 2;
        float q1 = edge_logit<VE, NW>(cA, xrv, a06, a04, xvA);
        float q2 = edge_logit<VE, NW>(cB, xrv, a06, a04, xvB);
#pragma unroll
        for (int d = 1; d < 16; d <<= 1) {
            q1 += __shfl_xor(q1, d, 64);
            q2 += __shfl_xor(q2, d, 64);
        }
        float w1 = __expf(q1), w2 = __expf(q2);
        s += w1 + w2;
#pragma unroll
        for (int j = 0; j < VE; ++j)
            acc[j] = fmaf(w1, xvA[j], fmaf(w2, xvB[j], acc[j]));
    }
    if (e < e1) {
        float q = edge_logit<VE, NW>(nA, xrv, a06, a04, xvA);
#pragma unroll
        for (int d = 1; d < 16; d <<= 1) q += __shfl_xor(q, d, 64);
        float we = __expf(q);
        s += we;
#pragma unroll
        for (int j = 0; j < VE; ++j) acc[j] = fmaf(we, xvA[j], acc[j]);
    }
    float r = 1.f / (s + 1e-16f);
#pragma unroll
    for (int v = 0; v < VE; v += 4) {
        float t[4];
#pragma unroll
        for (int j = 0; j < 4; ++j) {
            int c = cbase + v + j;
            float val = acc[v + j] * r + bias[c];
            float y = bng[c] * (val - bnm[c]) * rsqrtf(bnv[c] + 1e-5f) + bnb[c];
            t[j] = fmaxf(y, 0.f);
        }
        uint2 qo;
        qo.x = pk_bf16(t[0], t[1]);
        qo.y = pk_bf16(t[2], t[3]);
        *(uint2*)(out_ + (size_t)node * HO + cbase + v) = qo;
    }
}

// ---------------- mean pool (h2 bf16 -> pooled fp32), vectorized ----------------
__global__ __launch_bounds__(128) void pool_kernel(const unsigned short* __restrict__ h2,
                                                   const int* __restrict__ gs,
                                                   float* __restrict__ pooled) {
    const int g = blockIdx.x;
    const int c4 = threadIdx.x * 4;   // 128 threads x 4 cols = 512
    const int s = gs[g], e = gs[g + 1];
    float a0 = 0.f, a1 = 0.f, a2 = 0.f, a3 = 0.f;
    for (int r = s; r < e; ++r) {
        uint2 q = *(const uint2*)(h2 + (size_t)r * HO2 + c4);
        a0 += __uint_as_float(q.x << 16);
        a1 += __uint_as_float(q.x & 0xffff0000u);
        a2 += __uint_as_float(q.y << 16);
        a3 += __uint_as_float(q.y & 0xffff0000u);
    }
    float inv = 1.f / fmaxf((float)(e - s), 1.f);
    float4 o; o.x = a0 * inv; o.y = a1 * inv; o.z = a2 * inv; o.w = a3 * inv;
    *(float4*)(pooled + (size_t)g * HO2 + c4) = o;
}

// ---------------- MLP head ----------------
__global__ __launch_bounds__(128) void mlp_kernel(const float* __restrict__ pooled,
                                                  const float* __restrict__ gf,
                                                  const float* __restrict__ fc1w,
                                                  const float* __restrict__ fc1b,
                                                  const float* __restrict__ fc2w,
                                                  const float* __restrict__ fc2b,
                                                  float* __restrict__ out) {
    __shared__ float z[704];
    __shared__ float red[2];
    const int g = blockIdx.x, t = threadIdx.x;
    for (int i = t; i < HO2; i += 128) z[i] = pooled[(size_t)g * HO2 + i];
    for (int i = t; i < GF_DIM; i += 128) z[HO2 + i] = gf[(size_t)g * GF_DIM + i];
    __syncthreads();
    float s = fc1b[t];
    for (int k = 0; k < Z_DIM; ++k) s += z[k] * fc1w[k * FC1_DIM + t];
    s = fmaxf(s, 0.f);              // relu (dropout = identity in eval)
    float c = s * fc2w[t];
#pragma unroll
    for (int d = 1; d < 64; d <<= 1) c += __shfl_xor(c, d, 64);
    if ((t & 63) == 0) red[t >> 6] = c;
    __syncthreads();
    if (t == 0) out[g] = red[0] + red[1] + fc2b[0];
}

// ---------------- launch ----------------
extern "C" void kernel_launch(void* const* d_in, const int* in_sizes, int n_in,
                              void* d_out, int out_size, void* d_ws, size_t ws_size,
                              hipStream_t stream) {
    float* out = (float*)d_out;
    if (ws_size < WS_REQUIRED) {
        diag_kernel<<<1, 256, 0, stream>>>(out, (float)(ws_size >> 20));
        return;
    }
    const float* x     = (const float*)d_in[0];
    const int*   ei    = (const int*)d_in[1];
    const int*   batch = (const int*)d_in[2];
    const float* gf    = (const float*)d_in[3];
    const float* Wl1   = (const float*)d_in[4];
    const float* bl1   = (const float*)d_in[5];
    const float* Wr1   = (const float*)d_in[6];
    const float* br1   = (const float*)d_in[7];
    const float* att1  = (const float*)d_in[8];
    const float* bias1 = (const float*)d_in[9];
    const float* bn1g  = (const float*)d_in[10];
    const float* bn1b  = (const float*)d_in[11];
    const float* bn1m  = (const float*)d_in[12];
    const float* bn1v  = (const float*)d_in[13];
    const float* Wl2   = (const float*)d_in[14];
    const float* bl2   = (const float*)d_in[15];
    const float* Wr2   = (const float*)d_in[16];
    const float* br2   = (const float*)d_in[17];
    const float* att2  = (const float*)d_in[18];
    const float* bias2 = (const float*)d_in[19];
    const float* bn2g  = (const float*)d_in[20];
    const float* bn2b  = (const float*)d_in[21];
    const float* bn2m  = (const float*)d_in[22];
    const float* bn2v  = (const float*)d_in[23];
    const float* fc1w  = (const float*)d_in[24];
    const float* fc1b  = (const float*)d_in[25];
    const float* fc2w  = (const float*)d_in[26];
    const float* fc2b  = (const float*)d_in[27];
    char* ws = (char*)d_ws;

    unsigned short* xl1  = (unsigned short*)(ws + OFF_XL1);
    unsigned short* xr1  = (unsigned short*)(ws + OFF_XR1);
    unsigned short* xlr2 = (unsigned short*)(ws + OFF_XLR2);
    unsigned short* h1   = (unsigned short*)(ws + OFF_H1);
    unsigned short* h2   = (unsigned short*)(ws + OFF_H2);
    int* deg     = (int*)(ws + OFF_DEG);
    int* rowptr  = (int*)(ws + OFF_ROWPTR);
    int* cursor  = (int*)(ws + OFF_CURSOR);
    int* col     = (int*)(ws + OFF_COL);
    int* gs      = (int*)(ws + OFF_GS);
    float* pooled= (float*)(ws + OFF_POOLED);
    unsigned short* Wt = (unsigned short*)(ws + OFF_WCAT);
    float* bcat  = (float*)(ws + OFF_BCAT);

    // fused setup (zero deg | gstart | pack W2) then CSR build
    setup_kernel<<<1221, 256, 0, stream>>>(deg, batch, gs, Wl2, Wr2, bl2, br2, Wt, bcat);
    count_kernel<<<(N_EDGES + 255) / 256, 256, 0, stream>>>(ei, deg);
    scan_kernel<<<1, 1024, 0, stream>>>(deg, rowptr, cursor);
    fill_kernel<<<(N_EDGES + 255) / 256, 256, 0, stream>>>(ei, cursor, col);

    // layer 1 (bf16 storage, fp32 accumulation); gat1: 4 edges/wave
    mm1_kernel<<<N_NODES / 8, 256, 0, stream>>>(x, Wl1, bl1, Wr1, br1, xl1, xr1);
    gat_node_kernel<64, 2><<<(N_NODES + 3) / 4, 256, 0, stream>>>(
        xl1, xr1, HO1, rowptr, col, att1, bias1, bn1g, bn1b, bn1m, bn1v, h1);

    // layer 2 (bf16 MFMA GEMM, double-buffered + r8-exact gat2)
    mm2_mfma_kernel<<<dim3(8, (N_NODES + 127) / 128), 256, 0, stream>>>(h1, Wt, bcat, xlr2);
    gat2_kernel<128><<<(N_NODES + 3) / 4, 256, 0, stream>>>(
        xlr2, xlr2 + HO2, 1024, rowptr, col, att2, bias2, bn2g, bn2b, bn2m, bn2v, h2);

    // pool + head
    pool_kernel<<<N_GRAPHS, 128, 0, stream>>>(h2, gs, pooled);
    mlp_kernel<<<N_GRAPHS, 128, 0, stream>>>(pooled, gf, fc1w, fc1b, fc2w, fc2b, out);
}